// Round 1
// baseline (1568.058 us; speedup 1.0000x reference)
//
#include <hip/hip_runtime.h>
#include <hip/hip_bf16.h>
#include <math.h>

#define NN 32768       // nodes
#define FD 128         // feature dim
#define DD 128         // embed dim
#define NE 524288      // edges
#define EN_TOT (NE + NN)
#define LL 8
#define HH 8
#define SS 1025        // tokens (K+1)

// ---------------- CSR build ----------------
__global__ void hist_kernel(const int* __restrict__ ei, int* __restrict__ cnt) {
    int i = blockIdx.x * 256 + threadIdx.x;
    if (i >= EN_TOT) return;
    int d = (i < NE) ? ei[NE + i] : (i - NE);
    atomicAdd(&cnt[d], 1);
}

__global__ void scan_kernel(const int* __restrict__ cnt, int* __restrict__ offs) {
    __shared__ int wsum[16];
    int t = threadIdx.x;              // 0..1023, each owns 32 elements
    int base = t * 32;
    int s = 0;
    #pragma unroll
    for (int j = 0; j < 32; ++j) s += cnt[base + j];
    int lane = t & 63, w = t >> 6;
    int v = s;
    #pragma unroll
    for (int d = 1; d < 64; d <<= 1) {
        int u = __shfl_up(v, d);
        if (lane >= d) v += u;
    }
    if (lane == 63) wsum[w] = v;
    __syncthreads();
    if (t == 0) {
        int a = 0;
        #pragma unroll
        for (int i = 0; i < 16; ++i) { int x = wsum[i]; wsum[i] = a; a += x; }
    }
    __syncthreads();
    int run = wsum[w] + (v - s);      // exclusive prefix of this thread's chunk
    #pragma unroll
    for (int j = 0; j < 32; ++j) { offs[base + j] = run; run += cnt[base + j]; }
    if (t == 1023) offs[NN] = run;
}

__global__ void scatter_kernel(const int* __restrict__ ei, const int* __restrict__ offs,
                               int* __restrict__ fill, int* __restrict__ csr) {
    int i = blockIdx.x * 256 + threadIdx.x;
    if (i >= EN_TOT) return;
    int s, d;
    if (i < NE) { s = ei[i]; d = ei[NE + i]; } else { s = d = i - NE; }
    int pos = offs[d] + atomicAdd(&fill[d], 1);
    csr[pos] = s;
}

// ---------------- generic fp32 GEMM: C = act(A@B + bias) + res ----------------
// BM=64 BN=64 BK=32, 256 threads, 4x4 micro-tile.
__device__ __forceinline__ float gelu_f(float x) {
    float x3 = x * x * x;
    return 0.5f * x * (1.f + tanhf(0.7978845608028654f * (x + 0.044715f * x3)));
}

template <bool GATHER>
__global__ void gemm_f32(const float* __restrict__ A, const float* __restrict__ B,
                         const float* __restrict__ bias, const float* res,
                         float* C, int M, int Nn, int K, int act,
                         const int* __restrict__ no, const float* __restrict__ gsrc) {
    __shared__ float As[32][66];   // [k][m], pad 66: ~2-way conflicts only
    __shared__ float Bs[32][72];   // [k][n], pad 72: float4-aligned rows
    int t = threadIdx.x;
    int bx = blockIdx.x, by = blockIdx.y;
    int tx = t & 15, ty = t >> 4;
    float acc[4][4] = {};
    int m0 = t >> 3;               // 0..31
    int kk4 = (t & 7) * 4;         // 0..28
    int kb0 = t >> 4;              // 0..15
    int n40 = (t & 15) * 4;        // 0..60

    for (int k0 = 0; k0 < K; k0 += 32) {
        __syncthreads();
        #pragma unroll
        for (int half = 0; half < 2; ++half) {
            int m = m0 + half * 32;
            int row = by * 64 + m;
            float4 v = {0.f, 0.f, 0.f, 0.f};
            if (row < M) {
                if (!GATHER) {
                    v = *(const float4*)&A[(size_t)row * K + k0 + kk4];
                } else {
                    int k = k0 + kk4;
                    int node = no[row * 32 + (k >> 7)];
                    v = *(const float4*)&gsrc[(size_t)node * 128 + (k & 127)];
                }
            }
            As[kk4 + 0][m] = v.x; As[kk4 + 1][m] = v.y;
            As[kk4 + 2][m] = v.z; As[kk4 + 3][m] = v.w;
        }
        #pragma unroll
        for (int half = 0; half < 2; ++half) {
            int kk = kb0 + half * 16;
            *(float4*)&Bs[kk][n40] = *(const float4*)&B[(size_t)(k0 + kk) * Nn + bx * 64 + n40];
        }
        __syncthreads();
        #pragma unroll
        for (int kk = 0; kk < 32; ++kk) {
            float a0 = As[kk][ty * 4 + 0];
            float a1 = As[kk][ty * 4 + 1];
            float a2 = As[kk][ty * 4 + 2];
            float a3 = As[kk][ty * 4 + 3];
            float4 b4 = *(float4*)&Bs[kk][tx * 4];
            acc[0][0] += a0 * b4.x; acc[0][1] += a0 * b4.y; acc[0][2] += a0 * b4.z; acc[0][3] += a0 * b4.w;
            acc[1][0] += a1 * b4.x; acc[1][1] += a1 * b4.y; acc[1][2] += a1 * b4.z; acc[1][3] += a1 * b4.w;
            acc[2][0] += a2 * b4.x; acc[2][1] += a2 * b4.y; acc[2][2] += a2 * b4.z; acc[2][3] += a2 * b4.w;
            acc[3][0] += a3 * b4.x; acc[3][1] += a3 * b4.y; acc[3][2] += a3 * b4.z; acc[3][3] += a3 * b4.w;
        }
    }
    #pragma unroll
    for (int i = 0; i < 4; ++i) {
        int row = by * 64 + ty * 4 + i;
        if (row < M) {
            #pragma unroll
            for (int j = 0; j < 4; ++j) {
                int col = bx * 64 + tx * 4 + j;
                float v = acc[i][j];
                if (bias) v += bias[col];
                if (act == 1) v = gelu_f(v);
                if (res) v += res[(size_t)row * Nn + col];
                C[(size_t)row * Nn + col] = v;
            }
        }
    }
}

// ---------------- GAT pieces ----------------
__global__ void dots_kernel(const float* __restrict__ hW, const float* __restrict__ asrc,
                            const float* __restrict__ adst, float* __restrict__ ss,
                            float* __restrict__ sd) {
    int lane = threadIdx.x & 63;
    int n = blockIdx.x * 4 + (threadIdx.x >> 6);
    float h0 = hW[(size_t)n * 128 + lane];
    float h1 = hW[(size_t)n * 128 + 64 + lane];
    float vs = h0 * asrc[lane] + h1 * asrc[64 + lane];
    float vd = h0 * adst[lane] + h1 * adst[64 + lane];
    #pragma unroll
    for (int m = 32; m >= 1; m >>= 1) { vs += __shfl_xor(vs, m); vd += __shfl_xor(vd, m); }
    if (lane == 0) { ss[n] = vs; sd[n] = vd; }
}

__global__ void gat_aggregate(const float* __restrict__ hW, const int* __restrict__ offs,
                              const int* __restrict__ csr, const float* __restrict__ ssrc,
                              const float* __restrict__ sdst, const float* __restrict__ bias,
                              float* __restrict__ out) {
    int lane = threadIdx.x & 63;
    int n = blockIdx.x * 4 + (threadIdx.x >> 6);
    int beg = offs[n], end = offs[n + 1];   // deg >= 1 (self loop)
    float sd = sdst[n];
    float mymax = -INFINITY;
    for (int p = beg + lane; p < end; p += 64) {
        float e = ssrc[csr[p]] + sd;
        e = (e >= 0.f) ? e : 0.2f * e;
        mymax = fmaxf(mymax, e);
    }
    #pragma unroll
    for (int m = 32; m >= 1; m >>= 1) mymax = fmaxf(mymax, __shfl_xor(mymax, m));
    float mysum = 0.f;
    for (int p = beg + lane; p < end; p += 64) {
        float e = ssrc[csr[p]] + sd;
        e = (e >= 0.f) ? e : 0.2f * e;
        mysum += __expf(e - mymax);
    }
    #pragma unroll
    for (int m = 32; m >= 1; m >>= 1) mysum += __shfl_xor(mysum, m);
    float inv = 1.f / mysum;
    float acc0 = 0.f, acc1 = 0.f;
    for (int p = beg; p < end; ++p) {
        int s = csr[p];                       // uniform across lanes -> broadcast
        float e = ssrc[s] + sd;
        e = (e >= 0.f) ? e : 0.2f * e;
        float al = __expf(e - mymax) * inv;
        acc0 += al * hW[(size_t)s * 128 + lane];
        acc1 += al * hW[(size_t)s * 128 + 64 + lane];
    }
    out[(size_t)n * 128 + lane] = acc0 + bias[lane];
    out[(size_t)n * 128 + 64 + lane] = acc1 + bias[64 + lane];
}

// ---------------- transformer pieces ----------------
__global__ void ln_kernel(const float* __restrict__ x, float* __restrict__ y,
                          const float* __restrict__ s, const float* __restrict__ b, int M) {
    int lane = threadIdx.x & 63;
    int row = blockIdx.x * 4 + (threadIdx.x >> 6);
    if (row >= M) return;
    float a0 = x[(size_t)row * 128 + lane];
    float a1 = x[(size_t)row * 128 + 64 + lane];
    float sm = a0 + a1;
    #pragma unroll
    for (int m = 32; m >= 1; m >>= 1) sm += __shfl_xor(sm, m);
    float mean = sm * (1.f / 128.f);
    float d0 = a0 - mean, d1 = a1 - mean;
    float vv = d0 * d0 + d1 * d1;
    #pragma unroll
    for (int m = 32; m >= 1; m >>= 1) vv += __shfl_xor(vv, m);
    float r = rsqrtf(vv * (1.f / 128.f) + 1e-5f);
    y[(size_t)row * 128 + lane] = d0 * r * s[lane] + b[lane];
    y[(size_t)row * 128 + 64 + lane] = d1 * r * s[64 + lane] + b[64 + lane];
}

// flash attention: dh=16, 16 lanes per query row, K/V tiles (64 keys) in LDS
__global__ void attn_kernel(const float* __restrict__ qkv, float* __restrict__ ao) {
    __shared__ float Kl[64][20];
    __shared__ float Vl[64][20];
    int h = blockIdx.y;
    int t = threadIdx.x;
    int sub = t & 15;
    int qr = blockIdx.x * 16 + (t >> 4);
    bool active = qr < SS;
    float q[16];
    if (active) {
        #pragma unroll
        for (int d = 0; d < 16; ++d) q[d] = qkv[(size_t)qr * 384 + h * 16 + d];
    }
    float m = -INFINITY, sum = 0.f;
    float acc[16] = {};
    for (int j0 = 0; j0 < SS; j0 += 64) {
        __syncthreads();
        int j = t >> 2, dg = (t & 3) * 4;
        if (j0 + j < SS) {
            const float* row = qkv + (size_t)(j0 + j) * 384 + h * 16 + dg;
            *(float4*)&Kl[j][dg] = *(const float4*)(row + 128);
            *(float4*)&Vl[j][dg] = *(const float4*)(row + 256);
        }
        __syncthreads();
        if (active) {
            int jmax = min(64, SS - j0);
            for (int jj = sub; jj < jmax; jj += 16) {
                float sc = 0.f;
                #pragma unroll
                for (int d = 0; d < 16; ++d) sc += q[d] * Kl[jj][d];
                sc *= 0.25f;
                if (sc <= m) {
                    float p = __expf(sc - m);
                    sum += p;
                    #pragma unroll
                    for (int d = 0; d < 16; ++d) acc[d] += p * Vl[jj][d];
                } else {
                    float c = __expf(m - sc);
                    sum = sum * c + 1.f;
                    #pragma unroll
                    for (int d = 0; d < 16; ++d) acc[d] = acc[d] * c + Vl[jj][d];
                    m = sc;
                }
            }
        }
    }
    if (active) {
        #pragma unroll
        for (int msk = 1; msk < 16; msk <<= 1) {
            float mo = __shfl_xor(m, msk);
            float so = __shfl_xor(sum, msk);
            float vo[16];
            #pragma unroll
            for (int d = 0; d < 16; ++d) vo[d] = __shfl_xor(acc[d], msk);
            float mn = fmaxf(m, mo);
            float c1 = __expf(m - mn), c2 = __expf(mo - mn);
            sum = sum * c1 + so * c2;
            #pragma unroll
            for (int d = 0; d < 16; ++d) acc[d] = acc[d] * c1 + vo[d] * c2;
            m = mn;
        }
        if (sub == 0) {
            float inv = 1.f / sum;
            #pragma unroll
            for (int d = 0; d < 16; ++d) ao[(size_t)qr * 128 + h * 16 + d] = acc[d] * inv;
        }
    }
}

__global__ void cls_copy(const float* __restrict__ c, float* __restrict__ t) {
    t[threadIdx.x] = c[threadIdx.x];
}

__global__ void classifier_kernel(const float* __restrict__ t, const float* __restrict__ Wc,
                                  const float* __restrict__ bc, float* __restrict__ out) {
    int j = threadIdx.x;
    if (j < 10) {
        float a = bc[j];
        #pragma unroll
        for (int k = 0; k < 128; ++k) a += t[k] * Wc[k * 10 + j];
        out[j] = a;
    }
}

// ---------------- launch ----------------
extern "C" void kernel_launch(void* const* d_in, const int* in_sizes, int n_in,
                              void* d_out, int out_size, void* d_ws, size_t ws_size,
                              hipStream_t stream) {
    (void)in_sizes; (void)n_in; (void)out_size; (void)ws_size;
    const float* x     = (const float*)d_in[0];
    const int*   ei    = (const int*)d_in[1];
    const int*   nord  = (const int*)d_in[2];
    const float* W_in  = (const float*)d_in[3];
    const float* b_in  = (const float*)d_in[4];
    const float* Wg1   = (const float*)d_in[5];
    const float* as1   = (const float*)d_in[6];
    const float* ad1   = (const float*)d_in[7];
    const float* bg1   = (const float*)d_in[8];
    const float* Wg2   = (const float*)d_in[9];
    const float* as2   = (const float*)d_in[10];
    const float* ad2   = (const float*)d_in[11];
    const float* bg2   = (const float*)d_in[12];
    const float* W_emb = (const float*)d_in[13];
    const float* b_emb = (const float*)d_in[14];
    const float* clst  = (const float*)d_in[15];
    const float* ln1s  = (const float*)d_in[16];
    const float* ln1b  = (const float*)d_in[17];
    const float* Wqkv  = (const float*)d_in[18];
    const float* bqkv  = (const float*)d_in[19];
    const float* Wo    = (const float*)d_in[20];
    const float* bo    = (const float*)d_in[21];
    const float* ln2s  = (const float*)d_in[22];
    const float* ln2b  = (const float*)d_in[23];
    const float* Wf1   = (const float*)d_in[24];
    const float* bf1   = (const float*)d_in[25];
    const float* Wf2   = (const float*)d_in[26];
    const float* bf2   = (const float*)d_in[27];
    const float* Wc    = (const float*)d_in[28];
    const float* bc    = (const float*)d_in[29];

    char* w = (char*)d_ws;
    size_t o = 0;
    auto ALLOC = [&](size_t nbytes) -> char* {
        char* p = w + o;
        o += (nbytes + 255) & ~(size_t)255;
        return p;
    };
    int*   cnt  = (int*)ALLOC((size_t)NN * 4);
    int*   fill = (int*)ALLOC((size_t)NN * 4);     // contiguous with cnt
    int*   offs = (int*)ALLOC((size_t)(NN + 1) * 4);
    int*   csr  = (int*)ALLOC((size_t)EN_TOT * 4);
    float* h0   = (float*)ALLOC((size_t)NN * 128 * 4);
    float* hW   = (float*)ALLOC((size_t)NN * 128 * 4);
    float* h1   = (float*)ALLOC((size_t)NN * 128 * 4);
    float* ssrc = (float*)ALLOC((size_t)NN * 4);
    float* sdst = (float*)ALLOC((size_t)NN * 4);
    float* tbuf = (float*)ALLOC((size_t)SS * 128 * 4);
    float* ubuf = (float*)ALLOC((size_t)SS * 128 * 4);
    float* qkvb = (float*)ALLOC((size_t)SS * 384 * 4);
    float* aob  = (float*)ALLOC((size_t)SS * 128 * 4);
    float* ffnb = (float*)ALLOC((size_t)SS * 512 * 4);
    float* h2   = h0;  // reuse: h0 dead after GAT1's GEMM consumes it

    dim3 blk(256);
    int egrid = (EN_TOT + 255) / 256;

    // CSR by dst (rebuilt every call; ws is poisoned between calls)
    hipMemsetAsync(cnt, 0, (size_t)NN * 8, stream);
    hist_kernel<<<egrid, blk, 0, stream>>>(ei, cnt);
    scan_kernel<<<1, 1024, 0, stream>>>(cnt, offs);
    scatter_kernel<<<egrid, blk, 0, stream>>>(ei, offs, fill, csr);

    // h0 = x @ W_in + b_in
    gemm_f32<false><<<dim3(2, 512), blk, 0, stream>>>(x, W_in, b_in, nullptr, h0,
                                                      NN, 128, 128, 0, nullptr, nullptr);
    // GAT 1
    gemm_f32<false><<<dim3(2, 512), blk, 0, stream>>>(h0, Wg1, nullptr, nullptr, hW,
                                                      NN, 128, 128, 0, nullptr, nullptr);
    dots_kernel<<<8192, blk, 0, stream>>>(hW, as1, ad1, ssrc, sdst);
    gat_aggregate<<<8192, blk, 0, stream>>>(hW, offs, csr, ssrc, sdst, bg1, h1);
    // GAT 2
    gemm_f32<false><<<dim3(2, 512), blk, 0, stream>>>(h1, Wg2, nullptr, nullptr, hW,
                                                      NN, 128, 128, 0, nullptr, nullptr);
    dots_kernel<<<8192, blk, 0, stream>>>(hW, as2, ad2, ssrc, sdst);
    gat_aggregate<<<8192, blk, 0, stream>>>(hW, offs, csr, ssrc, sdst, bg2, h2);

    // tokens: t[0] = cls, t[1..] = gathered cluster embedding
    cls_copy<<<1, 128, 0, stream>>>(clst, tbuf);
    gemm_f32<true><<<dim3(2, 16), blk, 0, stream>>>(nullptr, W_emb, b_emb, nullptr, tbuf + 128,
                                                    1024, 128, 4096, 0, nord, h2);

    for (int l = 0; l < LL; ++l) {
        ln_kernel<<<257, blk, 0, stream>>>(tbuf, ubuf, ln1s + l * 128, ln1b + l * 128, SS);
        gemm_f32<false><<<dim3(6, 17), blk, 0, stream>>>(ubuf, Wqkv + (size_t)l * 128 * 384,
                                                         bqkv + l * 384, nullptr, qkvb,
                                                         SS, 384, 128, 0, nullptr, nullptr);
        attn_kernel<<<dim3(65, 8), blk, 0, stream>>>(qkvb, aob);
        gemm_f32<false><<<dim3(2, 17), blk, 0, stream>>>(aob, Wo + (size_t)l * 128 * 128,
                                                         bo + l * 128, tbuf, tbuf,
                                                         SS, 128, 128, 0, nullptr, nullptr);
        ln_kernel<<<257, blk, 0, stream>>>(tbuf, ubuf, ln2s + l * 128, ln2b + l * 128, SS);
        gemm_f32<false><<<dim3(8, 17), blk, 0, stream>>>(ubuf, Wf1 + (size_t)l * 128 * 512,
                                                         bf1 + l * 512, nullptr, ffnb,
                                                         SS, 512, 128, 1, nullptr, nullptr);
        gemm_f32<false><<<dim3(2, 17), blk, 0, stream>>>(ffnb, Wf2 + (size_t)l * 512 * 128,
                                                         bf2 + l * 128, tbuf, tbuf,
                                                         SS, 128, 512, 0, nullptr, nullptr);
    }
    classifier_kernel<<<1, 64, 0, stream>>>(tbuf, Wc, bc, (float*)d_out);
}

// Round 2
// 1120.319 us; speedup vs baseline: 1.3997x; 1.3997x over previous
//
#include <hip/hip_runtime.h>
#include <hip/hip_bf16.h>
#include <math.h>

#define NN 32768       // nodes
#define NE 524288      // edges
#define EN_TOT (NE + NN)
#define LL 8
#define SS 1025        // tokens (K+1)
#define SPLIT 16       // split-K for embedding gemm

// ---------------- CSR build ----------------
__global__ void hist_kernel(const int* __restrict__ ei, int* __restrict__ cnt) {
    int i = blockIdx.x * 256 + threadIdx.x;
    if (i >= EN_TOT) return;
    int d = (i < NE) ? ei[NE + i] : (i - NE);
    atomicAdd(&cnt[d], 1);
}

__global__ void scan_kernel(const int* __restrict__ cnt, int* __restrict__ offs) {
    __shared__ int wsum[16];
    int t = threadIdx.x;              // 0..1023, each owns 32 elements
    int base = t * 32;
    int s = 0;
    #pragma unroll
    for (int j = 0; j < 32; ++j) s += cnt[base + j];
    int lane = t & 63, w = t >> 6;
    int v = s;
    #pragma unroll
    for (int d = 1; d < 64; d <<= 1) {
        int u = __shfl_up(v, d);
        if (lane >= d) v += u;
    }
    if (lane == 63) wsum[w] = v;
    __syncthreads();
    if (t == 0) {
        int a = 0;
        #pragma unroll
        for (int i = 0; i < 16; ++i) { int x = wsum[i]; wsum[i] = a; a += x; }
    }
    __syncthreads();
    int run = wsum[w] + (v - s);
    #pragma unroll
    for (int j = 0; j < 32; ++j) { offs[base + j] = run; run += cnt[base + j]; }
    if (t == 1023) offs[NN] = run;
}

__global__ void scatter_kernel(const int* __restrict__ ei, const int* __restrict__ offs,
                               int* __restrict__ fill, int* __restrict__ csr) {
    int i = blockIdx.x * 256 + threadIdx.x;
    if (i >= EN_TOT) return;
    int s, d;
    if (i < NE) { s = ei[i]; d = ei[NE + i]; } else { s = d = i - NE; }
    int pos = offs[d] + atomicAdd(&fill[d], 1);
    csr[pos] = s;
}

// ---------------- generic fp32 GEMM ----------------
__device__ __forceinline__ float gelu_f(float x) {
    float x3 = x * x * x;
    return 0.5f * x * (1.f + tanhf(0.7978845608028654f * (x + 0.044715f * x3)));
}

__global__ void gemm_f32(const float* __restrict__ A, const float* __restrict__ B,
                         const float* __restrict__ bias, const float* res,
                         float* C, int M, int Nn, int K) {
    __shared__ float As[32][66];
    __shared__ float Bs[32][72];
    int t = threadIdx.x;
    int bx = blockIdx.x, by = blockIdx.y;
    int tx = t & 15, ty = t >> 4;
    float acc[4][4] = {};
    int m0 = t >> 3;
    int kk4 = (t & 7) * 4;
    int kb0 = t >> 4;
    int n40 = (t & 15) * 4;

    for (int k0 = 0; k0 < K; k0 += 32) {
        __syncthreads();
        #pragma unroll
        for (int half = 0; half < 2; ++half) {
            int m = m0 + half * 32;
            int row = by * 64 + m;
            float4 v = {0.f, 0.f, 0.f, 0.f};
            if (row < M) v = *(const float4*)&A[(size_t)row * K + k0 + kk4];
            As[kk4 + 0][m] = v.x; As[kk4 + 1][m] = v.y;
            As[kk4 + 2][m] = v.z; As[kk4 + 3][m] = v.w;
        }
        #pragma unroll
        for (int half = 0; half < 2; ++half) {
            int kk = kb0 + half * 16;
            *(float4*)&Bs[kk][n40] = *(const float4*)&B[(size_t)(k0 + kk) * Nn + bx * 64 + n40];
        }
        __syncthreads();
        #pragma unroll
        for (int kk = 0; kk < 32; ++kk) {
            float a0 = As[kk][ty * 4 + 0];
            float a1 = As[kk][ty * 4 + 1];
            float a2 = As[kk][ty * 4 + 2];
            float a3 = As[kk][ty * 4 + 3];
            float4 b4 = *(float4*)&Bs[kk][tx * 4];
            acc[0][0] += a0 * b4.x; acc[0][1] += a0 * b4.y; acc[0][2] += a0 * b4.z; acc[0][3] += a0 * b4.w;
            acc[1][0] += a1 * b4.x; acc[1][1] += a1 * b4.y; acc[1][2] += a1 * b4.z; acc[1][3] += a1 * b4.w;
            acc[2][0] += a2 * b4.x; acc[2][1] += a2 * b4.y; acc[2][2] += a2 * b4.z; acc[2][3] += a2 * b4.w;
            acc[3][0] += a3 * b4.x; acc[3][1] += a3 * b4.y; acc[3][2] += a3 * b4.z; acc[3][3] += a3 * b4.w;
        }
    }
    #pragma unroll
    for (int i = 0; i < 4; ++i) {
        int row = by * 64 + ty * 4 + i;
        if (row < M) {
            #pragma unroll
            for (int j = 0; j < 4; ++j) {
                int col = bx * 64 + tx * 4 + j;
                float v = acc[i][j];
                if (bias) v += bias[col];
                if (res) v += res[(size_t)row * Nn + col];
                C[(size_t)row * Nn + col] = v;
            }
        }
    }
}

__global__ void bcomb_kernel(const float* __restrict__ b_in, const float* __restrict__ Wg1,
                             float* __restrict__ bcomb) {
    int n = threadIdx.x;  // 128
    float s = 0.f;
    for (int k = 0; k < 128; ++k) s += b_in[k] * Wg1[k * 128 + n];
    bcomb[n] = s;
}

// ---------------- split-K gathered embedding GEMM ----------------
// partial[sp][m][n] = sum over k in [sp*256,(sp+1)*256) of h[no[m*32 + k/128]][k%128] * W[k][n]
__global__ void emb_gemm(const float* __restrict__ h, const float* __restrict__ W,
                         const int* __restrict__ no, float* __restrict__ pbuf) {
    __shared__ float As[32][66];
    __shared__ float Bs[32][72];
    int t = threadIdx.x;
    int bx = blockIdx.x, by = blockIdx.y, sp = blockIdx.z;
    int tx = t & 15, ty = t >> 4;
    float acc[4][4] = {};
    int m0 = t >> 3;
    int kk4 = (t & 7) * 4;
    int kb0 = t >> 4;
    int n40 = (t & 15) * 4;
    int kbase = sp * 256;

    for (int k0 = 0; k0 < 256; k0 += 32) {
        __syncthreads();
        #pragma unroll
        for (int half = 0; half < 2; ++half) {
            int m = m0 + half * 32;
            int row = by * 64 + m;
            int kg = kbase + k0 + kk4;
            int node = no[row * 32 + (kg >> 7)];
            float4 v = *(const float4*)&h[(size_t)node * 128 + (kg & 127)];
            As[kk4 + 0][m] = v.x; As[kk4 + 1][m] = v.y;
            As[kk4 + 2][m] = v.z; As[kk4 + 3][m] = v.w;
        }
        #pragma unroll
        for (int half = 0; half < 2; ++half) {
            int kk = kb0 + half * 16;
            *(float4*)&Bs[kk][n40] = *(const float4*)&W[(size_t)(kbase + k0 + kk) * 128 + bx * 64 + n40];
        }
        __syncthreads();
        #pragma unroll
        for (int kk = 0; kk < 32; ++kk) {
            float a0 = As[kk][ty * 4 + 0];
            float a1 = As[kk][ty * 4 + 1];
            float a2 = As[kk][ty * 4 + 2];
            float a3 = As[kk][ty * 4 + 3];
            float4 b4 = *(float4*)&Bs[kk][tx * 4];
            acc[0][0] += a0 * b4.x; acc[0][1] += a0 * b4.y; acc[0][2] += a0 * b4.z; acc[0][3] += a0 * b4.w;
            acc[1][0] += a1 * b4.x; acc[1][1] += a1 * b4.y; acc[1][2] += a1 * b4.z; acc[1][3] += a1 * b4.w;
            acc[2][0] += a2 * b4.x; acc[2][1] += a2 * b4.y; acc[2][2] += a2 * b4.z; acc[2][3] += a2 * b4.w;
            acc[3][0] += a3 * b4.x; acc[3][1] += a3 * b4.y; acc[3][2] += a3 * b4.z; acc[3][3] += a3 * b4.w;
        }
    }
    float* C = pbuf + (size_t)sp * (1024 * 128);
    #pragma unroll
    for (int i = 0; i < 4; ++i) {
        int row = by * 64 + ty * 4 + i;
        #pragma unroll
        for (int j = 0; j < 4; ++j)
            C[(size_t)row * 128 + bx * 64 + tx * 4 + j] = acc[i][j];
    }
}

__global__ void emb_reduce(const float* __restrict__ pbuf, const float* __restrict__ b_emb,
                           float* __restrict__ out) {
    int i = blockIdx.x * 256 + threadIdx.x;   // 0..131071
    float s = b_emb[i & 127];
    #pragma unroll
    for (int sp = 0; sp < SPLIT; ++sp) s += pbuf[(size_t)sp * 131072 + i];
    out[i] = s;
}

// ---------------- GAT pieces ----------------
__global__ void dots_kernel(const float* __restrict__ hW, const float* __restrict__ asrc,
                            const float* __restrict__ adst, float* __restrict__ ss,
                            float* __restrict__ sd) {
    int lane = threadIdx.x & 63;
    int n = blockIdx.x * 4 + (threadIdx.x >> 6);
    float h0 = hW[(size_t)n * 128 + lane];
    float h1 = hW[(size_t)n * 128 + 64 + lane];
    float vs = h0 * asrc[lane] + h1 * asrc[64 + lane];
    float vd = h0 * adst[lane] + h1 * adst[64 + lane];
    #pragma unroll
    for (int m = 32; m >= 1; m >>= 1) { vs += __shfl_xor(vs, m); vd += __shfl_xor(vd, m); }
    if (lane == 0) { ss[n] = vs; sd[n] = vd; }
}

__global__ void gat_aggregate(const float* __restrict__ hW, const int* __restrict__ offs,
                              const int* __restrict__ csr, const float* __restrict__ ssrc,
                              const float* __restrict__ sdst, const float* __restrict__ bias,
                              float* __restrict__ out) {
    int lane = threadIdx.x & 63;
    int n = blockIdx.x * 4 + (threadIdx.x >> 6);
    int beg = offs[n], end = offs[n + 1];
    float sd = sdst[n];
    float mymax = -INFINITY;
    for (int p = beg + lane; p < end; p += 64) {
        float e = ssrc[csr[p]] + sd;
        e = (e >= 0.f) ? e : 0.2f * e;
        mymax = fmaxf(mymax, e);
    }
    #pragma unroll
    for (int m = 32; m >= 1; m >>= 1) mymax = fmaxf(mymax, __shfl_xor(mymax, m));
    float mysum = 0.f;
    for (int p = beg + lane; p < end; p += 64) {
        float e = ssrc[csr[p]] + sd;
        e = (e >= 0.f) ? e : 0.2f * e;
        mysum += __expf(e - mymax);
    }
    #pragma unroll
    for (int m = 32; m >= 1; m >>= 1) mysum += __shfl_xor(mysum, m);
    float inv = 1.f / mysum;
    float acc0 = 0.f, acc1 = 0.f;
    for (int p = beg; p < end; ++p) {
        int s = csr[p];
        float e = ssrc[s] + sd;
        e = (e >= 0.f) ? e : 0.2f * e;
        float al = __expf(e - mymax) * inv;
        acc0 += al * hW[(size_t)s * 128 + lane];
        acc1 += al * hW[(size_t)s * 128 + 64 + lane];
    }
    out[(size_t)n * 128 + lane] = acc0 + bias[lane];
    out[(size_t)n * 128 + 64 + lane] = acc1 + bias[64 + lane];
}

// ---------------- fused transformer kernels ----------------
// A: u = LN1(t) per row; qkv = u @ Wq + bq.  16 rows/block, 256 threads.
__global__ __launch_bounds__(256) void fused_ln_qkv(
        const float* __restrict__ tb, const float* __restrict__ s1, const float* __restrict__ b1,
        const float* __restrict__ Wq, const float* __restrict__ bq, float* __restrict__ qkv) {
    __shared__ float u[16][128];
    __shared__ float ws[32 * 384];
    int t = threadIdx.x;
    int r0 = blockIdx.x * 16;
    {   // LN: 16-lane group per row
        int rw = t >> 4, l16 = t & 15, kb = l16 * 8;
        int row = r0 + rw;
        float4 x0 = {0, 0, 0, 0}, x1 = {0, 0, 0, 0};
        if (row < SS) {
            x0 = *(const float4*)&tb[(size_t)row * 128 + kb];
            x1 = *(const float4*)&tb[(size_t)row * 128 + kb + 4];
        }
        float sm = x0.x + x0.y + x0.z + x0.w + x1.x + x1.y + x1.z + x1.w;
        #pragma unroll
        for (int m = 8; m >= 1; m >>= 1) sm += __shfl_xor(sm, m);
        float mean = sm * (1.f / 128.f);
        float d[8] = {x0.x - mean, x0.y - mean, x0.z - mean, x0.w - mean,
                      x1.x - mean, x1.y - mean, x1.z - mean, x1.w - mean};
        float vv = 0.f;
        #pragma unroll
        for (int j = 0; j < 8; ++j) vv += d[j] * d[j];
        #pragma unroll
        for (int m = 8; m >= 1; m >>= 1) vv += __shfl_xor(vv, m);
        float rs = rsqrtf(vv * (1.f / 128.f) + 1e-5f);
        #pragma unroll
        for (int j = 0; j < 8; ++j) u[rw][kb + j] = d[j] * rs * s1[kb + j] + b1[kb + j];
    }
    int wv = t >> 6, ln = t & 63;
    float acc[4][6] = {};
    for (int k0 = 0; k0 < 128; k0 += 32) {
        __syncthreads();
        const float4* src = (const float4*)&Wq[(size_t)k0 * 384];
        #pragma unroll
        for (int i = 0; i < 12; ++i) ((float4*)ws)[i * 256 + t] = src[i * 256 + t];
        __syncthreads();
        #pragma unroll
        for (int kq = 0; kq < 32; kq += 4) {
            float a4[4][4];
            #pragma unroll
            for (int i = 0; i < 4; ++i)
                *(float4*)a4[i] = *(const float4*)&u[wv * 4 + i][k0 + kq];
            #pragma unroll
            for (int q = 0; q < 4; ++q) {
                float b[6];
                #pragma unroll
                for (int j = 0; j < 6; ++j) b[j] = ws[(kq + q) * 384 + ln + 64 * j];
                #pragma unroll
                for (int i = 0; i < 4; ++i)
                    #pragma unroll
                    for (int j = 0; j < 6; ++j) acc[i][j] += a4[i][q] * b[j];
            }
        }
    }
    #pragma unroll
    for (int i = 0; i < 4; ++i) {
        int row = r0 + wv * 4 + i;
        if (row < SS) {
            #pragma unroll
            for (int j = 0; j < 6; ++j) {
                int c = ln + 64 * j;
                qkv[(size_t)row * 384 + c] = acc[i][j] + bq[c];
            }
        }
    }
}

// C: tn = o@Wo + bo + t; u = LN2(tn); g = gelu(u@Wf1+bf1); t = tn + g@Wf2 + bf2
__global__ __launch_bounds__(256) void fused_proj_ffn(
        const float* __restrict__ ao, const float* __restrict__ Wo, const float* __restrict__ bo,
        const float* __restrict__ s2, const float* __restrict__ b2,
        const float* __restrict__ Wf1, const float* __restrict__ bf1,
        const float* __restrict__ Wf2, const float* __restrict__ bf2,
        float* __restrict__ tb) {
    __shared__ float bufA[16][128];   // o rows, later u
    __shared__ float tn[16][128];
    __shared__ float g[16][512];
    __shared__ float ws[8192];        // 32KB weight stage
    int t = threadIdx.x;
    int r0 = blockIdx.x * 16;
    int wv = t >> 6, ln = t & 63;
    {   // stage o rows
        int rw = t >> 4, l16 = t & 15, kb = l16 * 8;
        int row = r0 + rw;
        float4 x0 = {0, 0, 0, 0}, x1 = {0, 0, 0, 0};
        if (row < SS) {
            x0 = *(const float4*)&ao[(size_t)row * 128 + kb];
            x1 = *(const float4*)&ao[(size_t)row * 128 + kb + 4];
        }
        *(float4*)&bufA[rw][kb] = x0;
        *(float4*)&bufA[rw][kb + 4] = x1;
    }
    // ---- proj: tn = o@Wo + bo + t ----
    float accP[4][2] = {};
    for (int k0 = 0; k0 < 128; k0 += 32) {
        __syncthreads();
        const float4* src = (const float4*)&Wo[(size_t)k0 * 128];
        #pragma unroll
        for (int i = 0; i < 4; ++i) ((float4*)ws)[i * 256 + t] = src[i * 256 + t];
        __syncthreads();
        #pragma unroll
        for (int kq = 0; kq < 32; kq += 4) {
            float a4[4][4];
            #pragma unroll
            for (int i = 0; i < 4; ++i)
                *(float4*)a4[i] = *(const float4*)&bufA[wv * 4 + i][k0 + kq];
            #pragma unroll
            for (int q = 0; q < 4; ++q) {
                float b0 = ws[(kq + q) * 128 + ln];
                float b1 = ws[(kq + q) * 128 + 64 + ln];
                #pragma unroll
                for (int i = 0; i < 4; ++i) {
                    accP[i][0] += a4[i][q] * b0;
                    accP[i][1] += a4[i][q] * b1;
                }
            }
        }
    }
    __syncthreads();   // done reading bufA(o); will rewrite as u later
    #pragma unroll
    for (int i = 0; i < 4; ++i) {
        int row = r0 + wv * 4 + i;
        #pragma unroll
        for (int j = 0; j < 2; ++j) {
            int c = ln + 64 * j;
            float v = 0.f;
            if (row < SS) {
                v = accP[i][j] + bo[c] + tb[(size_t)row * 128 + c];
                tb[(size_t)row * 128 + c] = v;
            }
            tn[wv * 4 + i][c] = v;
        }
    }
    __syncthreads();
    {   // LN2: tn -> bufA(u)
        int rw = t >> 4, l16 = t & 15, kb = l16 * 8;
        float4 x0 = *(const float4*)&tn[rw][kb];
        float4 x1 = *(const float4*)&tn[rw][kb + 4];
        float sm = x0.x + x0.y + x0.z + x0.w + x1.x + x1.y + x1.z + x1.w;
        #pragma unroll
        for (int m = 8; m >= 1; m >>= 1) sm += __shfl_xor(sm, m);
        float mean = sm * (1.f / 128.f);
        float d[8] = {x0.x - mean, x0.y - mean, x0.z - mean, x0.w - mean,
                      x1.x - mean, x1.y - mean, x1.z - mean, x1.w - mean};
        float vv = 0.f;
        #pragma unroll
        for (int j = 0; j < 8; ++j) vv += d[j] * d[j];
        #pragma unroll
        for (int m = 8; m >= 1; m >>= 1) vv += __shfl_xor(vv, m);
        float rs = rsqrtf(vv * (1.f / 128.f) + 1e-5f);
        #pragma unroll
        for (int j = 0; j < 8; ++j) bufA[rw][kb + j] = d[j] * rs * s2[kb + j] + b2[kb + j];
    }
    // ---- ffn1: g = gelu(u@Wf1 + bf1) ----
    float accF[4][8] = {};
    for (int k0 = 0; k0 < 128; k0 += 16) {
        __syncthreads();
        const float4* src = (const float4*)&Wf1[(size_t)k0 * 512];
        #pragma unroll
        for (int i = 0; i < 8; ++i) ((float4*)ws)[i * 256 + t] = src[i * 256 + t];
        __syncthreads();
        #pragma unroll
        for (int kq = 0; kq < 16; kq += 4) {
            float a4[4][4];
            #pragma unroll
            for (int i = 0; i < 4; ++i)
                *(float4*)a4[i] = *(const float4*)&bufA[wv * 4 + i][k0 + kq];
            #pragma unroll
            for (int q = 0; q < 4; ++q) {
                float b[8];
                #pragma unroll
                for (int j = 0; j < 8; ++j) b[j] = ws[(kq + q) * 512 + ln + 64 * j];
                #pragma unroll
                for (int i = 0; i < 4; ++i)
                    #pragma unroll
                    for (int j = 0; j < 8; ++j) accF[i][j] += a4[i][q] * b[j];
            }
        }
    }
    __syncthreads();
    #pragma unroll
    for (int i = 0; i < 4; ++i)
        #pragma unroll
        for (int j = 0; j < 8; ++j) {
            int c = ln + 64 * j;
            g[wv * 4 + i][c] = gelu_f(accF[i][j] + bf1[c]);
        }
    // ---- ffn2: out = tn + g@Wf2 + bf2 ----
    float accO[4][2] = {};
    for (int k0 = 0; k0 < 512; k0 += 64) {
        __syncthreads();
        const float4* src = (const float4*)&Wf2[(size_t)k0 * 128];
        #pragma unroll
        for (int i = 0; i < 8; ++i) ((float4*)ws)[i * 256 + t] = src[i * 256 + t];
        __syncthreads();
        #pragma unroll
        for (int kq = 0; kq < 64; kq += 4) {
            float a4[4][4];
            #pragma unroll
            for (int i = 0; i < 4; ++i)
                *(float4*)a4[i] = *(const float4*)&g[wv * 4 + i][k0 + kq];
            #pragma unroll
            for (int q = 0; q < 4; ++q) {
                float b0 = ws[(kq + q) * 128 + ln];
                float b1 = ws[(kq + q) * 128 + 64 + ln];
                #pragma unroll
                for (int i = 0; i < 4; ++i) {
                    accO[i][0] += a4[i][q] * b0;
                    accO[i][1] += a4[i][q] * b1;
                }
            }
        }
    }
    #pragma unroll
    for (int i = 0; i < 4; ++i) {
        int row = r0 + wv * 4 + i;
        if (row < SS) {
            #pragma unroll
            for (int j = 0; j < 2; ++j) {
                int c = ln + 64 * j;
                tb[(size_t)row * 128 + c] = accO[i][j] + bf2[c] + tn[wv * 4 + i][c];
            }
        }
    }
}

// flash attention: dh=16, 16 lanes per query row, K/V tiles (64 keys) in LDS
__global__ void attn_kernel(const float* __restrict__ qkv, float* __restrict__ ao) {
    __shared__ float Kl[64][20];
    __shared__ float Vl[64][20];
    int h = blockIdx.y;
    int t = threadIdx.x;
    int sub = t & 15;
    int qr = blockIdx.x * 16 + (t >> 4);
    bool active = qr < SS;
    float q[16];
    if (active) {
        #pragma unroll
        for (int d = 0; d < 16; ++d) q[d] = qkv[(size_t)qr * 384 + h * 16 + d];
    }
    float m = -INFINITY, sum = 0.f;
    float acc[16] = {};
    for (int j0 = 0; j0 < SS; j0 += 64) {
        __syncthreads();
        int j = t >> 2, dg = (t & 3) * 4;
        if (j0 + j < SS) {
            const float* row = qkv + (size_t)(j0 + j) * 384 + h * 16 + dg;
            *(float4*)&Kl[j][dg] = *(const float4*)(row + 128);
            *(float4*)&Vl[j][dg] = *(const float4*)(row + 256);
        }
        __syncthreads();
        if (active) {
            int jmax = min(64, SS - j0);
            for (int jj = sub; jj < jmax; jj += 16) {
                float sc = 0.f;
                #pragma unroll
                for (int d = 0; d < 16; ++d) sc += q[d] * Kl[jj][d];
                sc *= 0.25f;
                if (sc <= m) {
                    float p = __expf(sc - m);
                    sum += p;
                    #pragma unroll
                    for (int d = 0; d < 16; ++d) acc[d] += p * Vl[jj][d];
                } else {
                    float c = __expf(m - sc);
                    sum = sum * c + 1.f;
                    #pragma unroll
                    for (int d = 0; d < 16; ++d) acc[d] = acc[d] * c + Vl[jj][d];
                    m = sc;
                }
            }
        }
    }
    if (active) {
        #pragma unroll
        for (int msk = 1; msk < 16; msk <<= 1) {
            float mo = __shfl_xor(m, msk);
            float so = __shfl_xor(sum, msk);
            float vo[16];
            #pragma unroll
            for (int d = 0; d < 16; ++d) vo[d] = __shfl_xor(acc[d], msk);
            float mn = fmaxf(m, mo);
            float c1 = __expf(m - mn), c2 = __expf(mo - mn);
            sum = sum * c1 + so * c2;
            #pragma unroll
            for (int d = 0; d < 16; ++d) acc[d] = acc[d] * c1 + vo[d] * c2;
            m = mn;
        }
        if (sub == 0) {
            float inv = 1.f / sum;
            #pragma unroll
            for (int d = 0; d < 16; ++d) ao[(size_t)qr * 128 + h * 16 + d] = acc[d] * inv;
        }
    }
}

__global__ void cls_copy(const float* __restrict__ c, float* __restrict__ t) {
    t[threadIdx.x] = c[threadIdx.x];
}

__global__ void classifier_kernel(const float* __restrict__ t, const float* __restrict__ Wc,
                                  const float* __restrict__ bc, float* __restrict__ out) {
    int j = threadIdx.x;
    if (j < 10) {
        float a = bc[j];
        #pragma unroll
        for (int k = 0; k < 128; ++k) a += t[k] * Wc[k * 10 + j];
        out[j] = a;
    }
}

// ---------------- launch ----------------
extern "C" void kernel_launch(void* const* d_in, const int* in_sizes, int n_in,
                              void* d_out, int out_size, void* d_ws, size_t ws_size,
                              hipStream_t stream) {
    (void)in_sizes; (void)n_in; (void)out_size; (void)ws_size;
    const float* x     = (const float*)d_in[0];
    const int*   ei    = (const int*)d_in[1];
    const int*   nord  = (const int*)d_in[2];
    const float* W_in  = (const float*)d_in[3];
    const float* b_in  = (const float*)d_in[4];
    const float* Wg1   = (const float*)d_in[5];
    const float* as1   = (const float*)d_in[6];
    const float* ad1   = (const float*)d_in[7];
    const float* bg1   = (const float*)d_in[8];
    const float* Wg2   = (const float*)d_in[9];
    const float* as2   = (const float*)d_in[10];
    const float* ad2   = (const float*)d_in[11];
    const float* bg2   = (const float*)d_in[12];
    const float* W_emb = (const float*)d_in[13];
    const float* b_emb = (const float*)d_in[14];
    const float* clst  = (const float*)d_in[15];
    const float* ln1s  = (const float*)d_in[16];
    const float* ln1b  = (const float*)d_in[17];
    const float* Wqkv  = (const float*)d_in[18];
    const float* bqkv  = (const float*)d_in[19];
    const float* Wo    = (const float*)d_in[20];
    const float* bo    = (const float*)d_in[21];
    const float* ln2s  = (const float*)d_in[22];
    const float* ln2b  = (const float*)d_in[23];
    const float* Wf1   = (const float*)d_in[24];
    const float* bf1   = (const float*)d_in[25];
    const float* Wf2   = (const float*)d_in[26];
    const float* bf2   = (const float*)d_in[27];
    const float* Wc    = (const float*)d_in[28];
    const float* bc    = (const float*)d_in[29];

    char* w = (char*)d_ws;
    size_t o = 0;
    auto ALLOC = [&](size_t nbytes) -> char* {
        char* p = w + o;
        o += (nbytes + 255) & ~(size_t)255;
        return p;
    };
    int*   cnt   = (int*)ALLOC((size_t)NN * 4);
    int*   fill  = (int*)ALLOC((size_t)NN * 4);   // contiguous with cnt
    int*   offs  = (int*)ALLOC((size_t)(NN + 1) * 4);
    int*   csr   = (int*)ALLOC((size_t)EN_TOT * 4);
    float* hA    = (float*)ALLOC((size_t)NN * 128 * 4);   // GAT2 output (h2)
    float* hW    = (float*)ALLOC((size_t)NN * 128 * 4);   // also pbuf (8MB needed)
    float* h1    = (float*)ALLOC((size_t)NN * 128 * 4);
    float* ssrc  = (float*)ALLOC((size_t)NN * 4);
    float* sdst  = (float*)ALLOC((size_t)NN * 4);
    float* tbuf  = (float*)ALLOC((size_t)SS * 128 * 4);
    float* qkvb  = (float*)ALLOC((size_t)SS * 384 * 4);
    float* aob   = (float*)ALLOC((size_t)SS * 128 * 4);
    float* Wcomb = (float*)ALLOC((size_t)128 * 128 * 4);
    float* bcomb = (float*)ALLOC((size_t)128 * 4);
    float* pbuf  = hW;   // reused: hW dead by embedding stage

    dim3 blk(256);
    int egrid = (EN_TOT + 255) / 256;

    // CSR by dst
    hipMemsetAsync(cnt, 0, (size_t)NN * 8, stream);
    hist_kernel<<<egrid, blk, 0, stream>>>(ei, cnt);
    scan_kernel<<<1, 1024, 0, stream>>>(cnt, offs);
    scatter_kernel<<<egrid, blk, 0, stream>>>(ei, offs, fill, csr);

    // Wcomb = W_in@Wg1 ; bcomb = b_in@Wg1  (h0 is only ever consumed via @Wg1)
    gemm_f32<<<dim3(2, 2), blk, 0, stream>>>(W_in, Wg1, nullptr, nullptr, Wcomb, 128, 128, 128);
    bcomb_kernel<<<1, 128, 0, stream>>>(b_in, Wg1, bcomb);

    // GAT 1: hW = x@Wcomb + bcomb
    gemm_f32<<<dim3(2, 512), blk, 0, stream>>>(x, Wcomb, bcomb, nullptr, hW, NN, 128, 128);
    dots_kernel<<<8192, blk, 0, stream>>>(hW, as1, ad1, ssrc, sdst);
    gat_aggregate<<<8192, blk, 0, stream>>>(hW, offs, csr, ssrc, sdst, bg1, h1);
    // GAT 2
    gemm_f32<<<dim3(2, 512), blk, 0, stream>>>(h1, Wg2, nullptr, nullptr, hW, NN, 128, 128);
    dots_kernel<<<8192, blk, 0, stream>>>(hW, as2, ad2, ssrc, sdst);
    gat_aggregate<<<8192, blk, 0, stream>>>(hW, offs, csr, ssrc, sdst, bg2, hA);

    // tokens
    cls_copy<<<1, 128, 0, stream>>>(clst, tbuf);
    emb_gemm<<<dim3(2, 16, SPLIT), blk, 0, stream>>>(hA, W_emb, nord, pbuf);
    emb_reduce<<<512, blk, 0, stream>>>(pbuf, b_emb, tbuf + 128);

    for (int l = 0; l < LL; ++l) {
        fused_ln_qkv<<<65, blk, 0, stream>>>(tbuf, ln1s + l * 128, ln1b + l * 128,
                                             Wqkv + (size_t)l * 128 * 384, bqkv + l * 384, qkvb);
        attn_kernel<<<dim3(65, 8), blk, 0, stream>>>(qkvb, aob);
        fused_proj_ffn<<<65, blk, 0, stream>>>(aob, Wo + (size_t)l * 128 * 128, bo + l * 128,
                                               ln2s + l * 128, ln2b + l * 128,
                                               Wf1 + (size_t)l * 128 * 512, bf1 + l * 512,
                                               Wf2 + (size_t)l * 512 * 128, bf2 + l * 128, tbuf);
    }
    classifier_kernel<<<1, 64, 0, stream>>>(tbuf, Wc, bc, (float*)d_out);
}

// Round 3
// 1058.027 us; speedup vs baseline: 1.4821x; 1.0589x over previous
//
#include <hip/hip_runtime.h>
#include <hip/hip_bf16.h>
#include <math.h>

#define NN 32768       // nodes
#define NE 524288      // edges
#define EN_TOT (NE + NN)
#define LL 8
#define SS 1025        // tokens (K+1)
#define SPLIT 16       // split-K for embedding gemm

// ---------------- CSR build ----------------
__global__ void hist_kernel(const int* __restrict__ ei, int* __restrict__ cnt) {
    int i = blockIdx.x * 256 + threadIdx.x;
    if (i >= EN_TOT) return;
    int d = (i < NE) ? ei[NE + i] : (i - NE);
    atomicAdd(&cnt[d], 1);
}

__global__ void scan_kernel(const int* __restrict__ cnt, int* __restrict__ offs) {
    __shared__ int wsum[16];
    int t = threadIdx.x;              // 0..1023, each owns 32 elements
    int base = t * 32;
    int s = 0;
    #pragma unroll
    for (int j = 0; j < 32; ++j) s += cnt[base + j];
    int lane = t & 63, w = t >> 6;
    int v = s;
    #pragma unroll
    for (int d = 1; d < 64; d <<= 1) {
        int u = __shfl_up(v, d);
        if (lane >= d) v += u;
    }
    if (lane == 63) wsum[w] = v;
    __syncthreads();
    if (t == 0) {
        int a = 0;
        #pragma unroll
        for (int i = 0; i < 16; ++i) { int x = wsum[i]; wsum[i] = a; a += x; }
    }
    __syncthreads();
    int run = wsum[w] + (v - s);
    #pragma unroll
    for (int j = 0; j < 32; ++j) { offs[base + j] = run; run += cnt[base + j]; }
    if (t == 1023) offs[NN] = run;
}

__global__ void scatter_kernel(const int* __restrict__ ei, const int* __restrict__ offs,
                               int* __restrict__ fill, int* __restrict__ csr) {
    int i = blockIdx.x * 256 + threadIdx.x;
    if (i >= EN_TOT) return;
    int s, d;
    if (i < NE) { s = ei[i]; d = ei[NE + i]; } else { s = d = i - NE; }
    int pos = offs[d] + atomicAdd(&fill[d], 1);
    csr[pos] = s;
}

// ---------------- generic fp32 GEMM ----------------
__device__ __forceinline__ float gelu_f(float x) {
    float x3 = x * x * x;
    return 0.5f * x * (1.f + tanhf(0.7978845608028654f * (x + 0.044715f * x3)));
}

__global__ void gemm_f32(const float* __restrict__ A, const float* __restrict__ B,
                         const float* __restrict__ bias, const float* res,
                         float* C, int M, int Nn, int K) {
    __shared__ float As[32][66];
    __shared__ float Bs[32][72];
    int t = threadIdx.x;
    int bx = blockIdx.x, by = blockIdx.y;
    int tx = t & 15, ty = t >> 4;
    float acc[4][4] = {};
    int m0 = t >> 3;
    int kk4 = (t & 7) * 4;
    int kb0 = t >> 4;
    int n40 = (t & 15) * 4;

    for (int k0 = 0; k0 < K; k0 += 32) {
        __syncthreads();
        #pragma unroll
        for (int half = 0; half < 2; ++half) {
            int m = m0 + half * 32;
            int row = by * 64 + m;
            float4 v = {0.f, 0.f, 0.f, 0.f};
            if (row < M) v = *(const float4*)&A[(size_t)row * K + k0 + kk4];
            As[kk4 + 0][m] = v.x; As[kk4 + 1][m] = v.y;
            As[kk4 + 2][m] = v.z; As[kk4 + 3][m] = v.w;
        }
        #pragma unroll
        for (int half = 0; half < 2; ++half) {
            int kk = kb0 + half * 16;
            *(float4*)&Bs[kk][n40] = *(const float4*)&B[(size_t)(k0 + kk) * Nn + bx * 64 + n40];
        }
        __syncthreads();
        #pragma unroll
        for (int kk = 0; kk < 32; ++kk) {
            float a0 = As[kk][ty * 4 + 0];
            float a1 = As[kk][ty * 4 + 1];
            float a2 = As[kk][ty * 4 + 2];
            float a3 = As[kk][ty * 4 + 3];
            float4 b4 = *(float4*)&Bs[kk][tx * 4];
            acc[0][0] += a0 * b4.x; acc[0][1] += a0 * b4.y; acc[0][2] += a0 * b4.z; acc[0][3] += a0 * b4.w;
            acc[1][0] += a1 * b4.x; acc[1][1] += a1 * b4.y; acc[1][2] += a1 * b4.z; acc[1][3] += a1 * b4.w;
            acc[2][0] += a2 * b4.x; acc[2][1] += a2 * b4.y; acc[2][2] += a2 * b4.z; acc[2][3] += a2 * b4.w;
            acc[3][0] += a3 * b4.x; acc[3][1] += a3 * b4.y; acc[3][2] += a3 * b4.z; acc[3][3] += a3 * b4.w;
        }
    }
    #pragma unroll
    for (int i = 0; i < 4; ++i) {
        int row = by * 64 + ty * 4 + i;
        if (row < M) {
            #pragma unroll
            for (int j = 0; j < 4; ++j) {
                int col = bx * 64 + tx * 4 + j;
                float v = acc[i][j];
                if (bias) v += bias[col];
                if (res) v += res[(size_t)row * Nn + col];
                C[(size_t)row * Nn + col] = v;
            }
        }
    }
}

__global__ void bcomb_kernel(const float* __restrict__ b_in, const float* __restrict__ Wg1,
                             float* __restrict__ bcomb) {
    int n = threadIdx.x;  // 128
    float s = 0.f;
    for (int k = 0; k < 128; ++k) s += b_in[k] * Wg1[k * 128 + n];
    bcomb[n] = s;
}

// ---------------- split-K gathered embedding GEMM ----------------
__global__ void emb_gemm(const float* __restrict__ h, const float* __restrict__ W,
                         const int* __restrict__ no, float* __restrict__ pbuf) {
    __shared__ float As[32][66];
    __shared__ float Bs[32][72];
    int t = threadIdx.x;
    int bx = blockIdx.x, by = blockIdx.y, sp = blockIdx.z;
    int tx = t & 15, ty = t >> 4;
    float acc[4][4] = {};
    int m0 = t >> 3;
    int kk4 = (t & 7) * 4;
    int kb0 = t >> 4;
    int n40 = (t & 15) * 4;
    int kbase = sp * 256;

    for (int k0 = 0; k0 < 256; k0 += 32) {
        __syncthreads();
        #pragma unroll
        for (int half = 0; half < 2; ++half) {
            int m = m0 + half * 32;
            int row = by * 64 + m;
            int kg = kbase + k0 + kk4;
            int node = no[row * 32 + (kg >> 7)];
            float4 v = *(const float4*)&h[(size_t)node * 128 + (kg & 127)];
            As[kk4 + 0][m] = v.x; As[kk4 + 1][m] = v.y;
            As[kk4 + 2][m] = v.z; As[kk4 + 3][m] = v.w;
        }
        #pragma unroll
        for (int half = 0; half < 2; ++half) {
            int kk = kb0 + half * 16;
            *(float4*)&Bs[kk][n40] = *(const float4*)&W[(size_t)(kbase + k0 + kk) * 128 + bx * 64 + n40];
        }
        __syncthreads();
        #pragma unroll
        for (int kk = 0; kk < 32; ++kk) {
            float a0 = As[kk][ty * 4 + 0];
            float a1 = As[kk][ty * 4 + 1];
            float a2 = As[kk][ty * 4 + 2];
            float a3 = As[kk][ty * 4 + 3];
            float4 b4 = *(float4*)&Bs[kk][tx * 4];
            acc[0][0] += a0 * b4.x; acc[0][1] += a0 * b4.y; acc[0][2] += a0 * b4.z; acc[0][3] += a0 * b4.w;
            acc[1][0] += a1 * b4.x; acc[1][1] += a1 * b4.y; acc[1][2] += a1 * b4.z; acc[1][3] += a1 * b4.w;
            acc[2][0] += a2 * b4.x; acc[2][1] += a2 * b4.y; acc[2][2] += a2 * b4.z; acc[2][3] += a2 * b4.w;
            acc[3][0] += a3 * b4.x; acc[3][1] += a3 * b4.y; acc[3][2] += a3 * b4.z; acc[3][3] += a3 * b4.w;
        }
    }
    float* C = pbuf + (size_t)sp * (1024 * 128);
    #pragma unroll
    for (int i = 0; i < 4; ++i) {
        int row = by * 64 + ty * 4 + i;
        #pragma unroll
        for (int j = 0; j < 4; ++j)
            C[(size_t)row * 128 + bx * 64 + tx * 4 + j] = acc[i][j];
    }
}

__global__ void emb_reduce(const float* __restrict__ pbuf, const float* __restrict__ b_emb,
                           float* __restrict__ out) {
    int i = blockIdx.x * 256 + threadIdx.x;   // 0..131071
    float s = b_emb[i & 127];
    #pragma unroll
    for (int sp = 0; sp < SPLIT; ++sp) s += pbuf[(size_t)sp * 131072 + i];
    out[i] = s;
}

// ---------------- GAT pieces ----------------
__global__ void dots_kernel(const float* __restrict__ hW, const float* __restrict__ asrc,
                            const float* __restrict__ adst, float* __restrict__ ss,
                            float* __restrict__ sd) {
    int lane = threadIdx.x & 63;
    int n = blockIdx.x * 4 + (threadIdx.x >> 6);
    float h0 = hW[(size_t)n * 128 + lane];
    float h1 = hW[(size_t)n * 128 + 64 + lane];
    float vs = h0 * asrc[lane] + h1 * asrc[64 + lane];
    float vd = h0 * adst[lane] + h1 * adst[64 + lane];
    #pragma unroll
    for (int m = 32; m >= 1; m >>= 1) { vs += __shfl_xor(vs, m); vd += __shfl_xor(vd, m); }
    if (lane == 0) { ss[n] = vs; sd[n] = vd; }
}

__global__ void gat_aggregate(const float* __restrict__ hW, const int* __restrict__ offs,
                              const int* __restrict__ csr, const float* __restrict__ ssrc,
                              const float* __restrict__ sdst, const float* __restrict__ bias,
                              float* __restrict__ out) {
    int lane = threadIdx.x & 63;
    int n = blockIdx.x * 4 + (threadIdx.x >> 6);
    int beg = offs[n], end = offs[n + 1];
    float sd = sdst[n];
    float mymax = -INFINITY;
    for (int p = beg + lane; p < end; p += 64) {
        float e = ssrc[csr[p]] + sd;
        e = (e >= 0.f) ? e : 0.2f * e;
        mymax = fmaxf(mymax, e);
    }
    #pragma unroll
    for (int m = 32; m >= 1; m >>= 1) mymax = fmaxf(mymax, __shfl_xor(mymax, m));
    float mysum = 0.f;
    for (int p = beg + lane; p < end; p += 64) {
        float e = ssrc[csr[p]] + sd;
        e = (e >= 0.f) ? e : 0.2f * e;
        mysum += __expf(e - mymax);
    }
    #pragma unroll
    for (int m = 32; m >= 1; m >>= 1) mysum += __shfl_xor(mysum, m);
    float inv = 1.f / mysum;
    float acc0 = 0.f, acc1 = 0.f;
    for (int p = beg; p < end; ++p) {
        int s = csr[p];
        float e = ssrc[s] + sd;
        e = (e >= 0.f) ? e : 0.2f * e;
        float al = __expf(e - mymax) * inv;
        acc0 += al * hW[(size_t)s * 128 + lane];
        acc1 += al * hW[(size_t)s * 128 + 64 + lane];
    }
    out[(size_t)n * 128 + lane] = acc0 + bias[lane];
    out[(size_t)n * 128 + 64 + lane] = acc1 + bias[64 + lane];
}

// ---------------- fused transformer kernels (4 rows/block, 257 blocks) ----------------
// u = LN1(t); qkv = u @ Wq + bq.  192 threads x 2 cols, b reused over 4 rows.
__global__ __launch_bounds__(256) void fused_ln_qkv(
        const float* __restrict__ tb, const float* __restrict__ s1, const float* __restrict__ b1,
        const float* __restrict__ Wq, const float* __restrict__ bq, float* __restrict__ qkv) {
    __shared__ float u[4][128];
    __shared__ float ws[16 * 384];   // 24 KB stage
    int t = threadIdx.x;
    int r0 = blockIdx.x * 4;
    {   // LN: 64 lanes per row
        int rw = t >> 6, lane = t & 63;
        int row = r0 + rw;
        float a0 = 0.f, a1 = 0.f;
        if (row < SS) {
            a0 = tb[(size_t)row * 128 + lane];
            a1 = tb[(size_t)row * 128 + 64 + lane];
        }
        float sm = a0 + a1;
        #pragma unroll
        for (int m = 32; m >= 1; m >>= 1) sm += __shfl_xor(sm, m);
        float mean = sm * (1.f / 128.f);
        float d0 = a0 - mean, d1 = a1 - mean;
        float vv = d0 * d0 + d1 * d1;
        #pragma unroll
        for (int m = 32; m >= 1; m >>= 1) vv += __shfl_xor(vv, m);
        float rs = rsqrtf(vv * (1.f / 128.f) + 1e-5f);
        u[rw][lane] = d0 * rs * s1[lane] + b1[lane];
        u[rw][64 + lane] = d1 * rs * s1[64 + lane] + b1[64 + lane];
    }
    float acc[4][2] = {};
    int c0 = t * 2;                  // threads 0..191 own cols {c0, c0+1}
    for (int k0 = 0; k0 < 128; k0 += 16) {
        __syncthreads();
        const float4* src = (const float4*)&Wq[(size_t)k0 * 384];
        #pragma unroll
        for (int i = 0; i < 6; ++i) ((float4*)ws)[i * 256 + t] = src[i * 256 + t];
        __syncthreads();
        if (c0 < 384) {
            #pragma unroll
            for (int kq = 0; kq < 16; kq += 4) {
                float a4[4][4];
                #pragma unroll
                for (int i = 0; i < 4; ++i)
                    *(float4*)a4[i] = *(const float4*)&u[i][k0 + kq];
                #pragma unroll
                for (int q = 0; q < 4; ++q) {
                    float2 b2 = *(const float2*)&ws[(kq + q) * 384 + c0];
                    #pragma unroll
                    for (int i = 0; i < 4; ++i) {
                        acc[i][0] += a4[i][q] * b2.x;
                        acc[i][1] += a4[i][q] * b2.y;
                    }
                }
            }
        }
    }
    if (c0 < 384) {
        float bq0 = bq[c0], bq1 = bq[c0 + 1];
        #pragma unroll
        for (int i = 0; i < 4; ++i) {
            int row = r0 + i;
            if (row < SS) {
                qkv[(size_t)row * 384 + c0] = acc[i][0] + bq0;
                qkv[(size_t)row * 384 + c0 + 1] = acc[i][1] + bq1;
            }
        }
    }
}

// tn = o@Wo + bo + t; u = LN2(tn); g = gelu(u@Wf1+bf1); t = tn + g@Wf2 + bf2
// proj/FFN2: 2-way k-split (col = t&127, kh = t>>7) + LDS reduce. FFN1: 2 cols/thread.
__global__ __launch_bounds__(256) void fused_proj_ffn(
        const float* __restrict__ ao, const float* __restrict__ Wo, const float* __restrict__ bo,
        const float* __restrict__ s2, const float* __restrict__ b2,
        const float* __restrict__ Wf1, const float* __restrict__ bf1,
        const float* __restrict__ Wf2, const float* __restrict__ bf2,
        float* __restrict__ tb) {
    __shared__ float bufA[4][128];    // o rows, later u
    __shared__ float tn[4][128];
    __shared__ float g[4][512];
    __shared__ float red[4][2][128];
    __shared__ float ws[8192];        // 32 KB weight stage
    int t = threadIdx.x;
    int r0 = blockIdx.x * 4;
    int lane = t & 63;
    int col = t & 127, kh = t >> 7;
    {   // stage o rows
        int rw = t >> 6;
        int row = r0 + rw;
        float a0 = 0.f, a1 = 0.f;
        if (row < SS) {
            a0 = ao[(size_t)row * 128 + lane];
            a1 = ao[(size_t)row * 128 + 64 + lane];
        }
        bufA[rw][lane] = a0;
        bufA[rw][64 + lane] = a1;
    }
    // ---- proj: 2 chunks of 64 k, each half-block does 32 ----
    float pp[4] = {};
    for (int k0 = 0; k0 < 128; k0 += 64) {
        __syncthreads();
        const float4* src = (const float4*)&Wo[(size_t)k0 * 128];
        #pragma unroll
        for (int i = 0; i < 8; ++i) ((float4*)ws)[i * 256 + t] = src[i * 256 + t];
        __syncthreads();
        int kb = kh * 32;
        #pragma unroll
        for (int kq = 0; kq < 32; kq += 4) {
            float a4[4][4];
            #pragma unroll
            for (int i = 0; i < 4; ++i)
                *(float4*)a4[i] = *(const float4*)&bufA[i][k0 + kb + kq];
            #pragma unroll
            for (int q = 0; q < 4; ++q) {
                float b = ws[(kb + kq + q) * 128 + col];
                #pragma unroll
                for (int i = 0; i < 4; ++i) pp[i] += a4[i][q] * b;
            }
        }
    }
    __syncthreads();
    #pragma unroll
    for (int i = 0; i < 4; ++i) red[i][kh][col] = pp[i];
    __syncthreads();
    if (t < 128) {
        #pragma unroll
        for (int i = 0; i < 4; ++i) {
            int row = r0 + i;
            float v = 0.f;
            if (row < SS) {
                v = red[i][0][t] + red[i][1][t] + bo[t] + tb[(size_t)row * 128 + t];
                tb[(size_t)row * 128 + t] = v;
            }
            tn[i][t] = v;
        }
    }
    __syncthreads();
    {   // LN2: tn -> bufA (u)
        int rw = t >> 6;
        float a0 = tn[rw][lane], a1 = tn[rw][64 + lane];
        float sm = a0 + a1;
        #pragma unroll
        for (int m = 32; m >= 1; m >>= 1) sm += __shfl_xor(sm, m);
        float mean = sm * (1.f / 128.f);
        float d0 = a0 - mean, d1 = a1 - mean;
        float vv = d0 * d0 + d1 * d1;
        #pragma unroll
        for (int m = 32; m >= 1; m >>= 1) vv += __shfl_xor(vv, m);
        float rs = rsqrtf(vv * (1.f / 128.f) + 1e-5f);
        bufA[rw][lane] = d0 * rs * s2[lane] + b2[lane];
        bufA[rw][64 + lane] = d1 * rs * s2[64 + lane] + b2[64 + lane];
    }
    // ---- ffn1: g = gelu(u@Wf1 + bf1), 2 cols/thread ----
    float accF[4][2] = {};
    int c2 = t * 2;
    for (int k0 = 0; k0 < 128; k0 += 16) {
        __syncthreads();
        const float4* src = (const float4*)&Wf1[(size_t)k0 * 512];
        #pragma unroll
        for (int i = 0; i < 8; ++i) ((float4*)ws)[i * 256 + t] = src[i * 256 + t];
        __syncthreads();
        #pragma unroll
        for (int kq = 0; kq < 16; kq += 4) {
            float a4[4][4];
            #pragma unroll
            for (int i = 0; i < 4; ++i)
                *(float4*)a4[i] = *(const float4*)&bufA[i][k0 + kq];
            #pragma unroll
            for (int q = 0; q < 4; ++q) {
                float2 b2v = *(const float2*)&ws[(kq + q) * 512 + c2];
                #pragma unroll
                for (int i = 0; i < 4; ++i) {
                    accF[i][0] += a4[i][q] * b2v.x;
                    accF[i][1] += a4[i][q] * b2v.y;
                }
            }
        }
    }
    #pragma unroll
    for (int i = 0; i < 4; ++i) {
        g[i][c2] = gelu_f(accF[i][0] + bf1[c2]);
        g[i][c2 + 1] = gelu_f(accF[i][1] + bf1[c2 + 1]);
    }
    // ---- ffn2: out = tn + g@Wf2 + bf2, k-split 2 x 256 ----
    float accO[4] = {};
    for (int k0 = 0; k0 < 512; k0 += 64) {
        __syncthreads();   // guards g writes (iter 0) and ws reuse
        const float4* src = (const float4*)&Wf2[(size_t)k0 * 128];
        #pragma unroll
        for (int i = 0; i < 8; ++i) ((float4*)ws)[i * 256 + t] = src[i * 256 + t];
        __syncthreads();
        int kb = kh * 32;
        #pragma unroll
        for (int kq = 0; kq < 32; kq += 4) {
            float a4[4][4];
            #pragma unroll
            for (int i = 0; i < 4; ++i)
                *(float4*)a4[i] = *(const float4*)&g[i][k0 + kb + kq];
            #pragma unroll
            for (int q = 0; q < 4; ++q) {
                float b = ws[(kb + kq + q) * 128 + col];
                #pragma unroll
                for (int i = 0; i < 4; ++i) accO[i] += a4[i][q] * b;
            }
        }
    }
    __syncthreads();
    #pragma unroll
    for (int i = 0; i < 4; ++i) red[i][kh][col] = accO[i];
    __syncthreads();
    if (t < 128) {
        #pragma unroll
        for (int i = 0; i < 4; ++i) {
            int row = r0 + i;
            if (row < SS)
                tb[(size_t)row * 128 + t] = red[i][0][t] + red[i][1][t] + bf2[t] + tn[i][t];
        }
    }
}

// flash attention: dh=16, 16 lanes per query row, K/V tiles (64 keys) in LDS
__global__ void attn_kernel(const float* __restrict__ qkv, float* __restrict__ ao) {
    __shared__ float Kl[64][20];
    __shared__ float Vl[64][20];
    int h = blockIdx.y;
    int t = threadIdx.x;
    int sub = t & 15;
    int qr = blockIdx.x * 16 + (t >> 4);
    bool active = qr < SS;
    float q[16];
    if (active) {
        #pragma unroll
        for (int d = 0; d < 16; ++d) q[d] = qkv[(size_t)qr * 384 + h * 16 + d];
    }
    float m = -INFINITY, sum = 0.f;
    float acc[16] = {};
    for (int j0 = 0; j0 < SS; j0 += 64) {
        __syncthreads();
        int j = t >> 2, dg = (t & 3) * 4;
        if (j0 + j < SS) {
            const float* row = qkv + (size_t)(j0 + j) * 384 + h * 16 + dg;
            *(float4*)&Kl[j][dg] = *(const float4*)(row + 128);
            *(float4*)&Vl[j][dg] = *(const float4*)(row + 256);
        }
        __syncthreads();
        if (active) {
            int jmax = min(64, SS - j0);
            for (int jj = sub; jj < jmax; jj += 16) {
                float4 ka = *(const float4*)&Kl[jj][0];
                float4 kb = *(const float4*)&Kl[jj][4];
                float4 kc = *(const float4*)&Kl[jj][8];
                float4 kd = *(const float4*)&Kl[jj][12];
                float sc = q[0]*ka.x + q[1]*ka.y + q[2]*ka.z + q[3]*ka.w
                         + q[4]*kb.x + q[5]*kb.y + q[6]*kb.z + q[7]*kb.w
                         + q[8]*kc.x + q[9]*kc.y + q[10]*kc.z + q[11]*kc.w
                         + q[12]*kd.x + q[13]*kd.y + q[14]*kd.z + q[15]*kd.w;
                sc *= 0.25f;
                float4 va = *(const float4*)&Vl[jj][0];
                float4 vb = *(const float4*)&Vl[jj][4];
                float4 vc = *(const float4*)&Vl[jj][8];
                float4 vd = *(const float4*)&Vl[jj][12];
                float vv[16] = {va.x, va.y, va.z, va.w, vb.x, vb.y, vb.z, vb.w,
                                vc.x, vc.y, vc.z, vc.w, vd.x, vd.y, vd.z, vd.w};
                if (sc <= m) {
                    float p = __expf(sc - m);
                    sum += p;
                    #pragma unroll
                    for (int d = 0; d < 16; ++d) acc[d] += p * vv[d];
                } else {
                    float c = __expf(m - sc);
                    sum = sum * c + 1.f;
                    #pragma unroll
                    for (int d = 0; d < 16; ++d) acc[d] = acc[d] * c + vv[d];
                    m = sc;
                }
            }
        }
    }
    if (active) {
        #pragma unroll
        for (int msk = 1; msk < 16; msk <<= 1) {
            float mo = __shfl_xor(m, msk);
            float so = __shfl_xor(sum, msk);
            float vo[16];
            #pragma unroll
            for (int d = 0; d < 16; ++d) vo[d] = __shfl_xor(acc[d], msk);
            float mn = fmaxf(m, mo);
            float c1 = __expf(m - mn), c2 = __expf(mo - mn);
            sum = sum * c1 + so * c2;
            #pragma unroll
            for (int d = 0; d < 16; ++d) acc[d] = acc[d] * c1 + vo[d] * c2;
            m = mn;
        }
        if (sub == 0) {
            float inv = 1.f / sum;
            #pragma unroll
            for (int d = 0; d < 16; ++d) ao[(size_t)qr * 128 + h * 16 + d] = acc[d] * inv;
        }
    }
}

__global__ void cls_copy(const float* __restrict__ c, float* __restrict__ t) {
    t[threadIdx.x] = c[threadIdx.x];
}

__global__ void classifier_kernel(const float* __restrict__ t, const float* __restrict__ Wc,
                                  const float* __restrict__ bc, float* __restrict__ out) {
    int j = threadIdx.x;
    if (j < 10) {
        float a = bc[j];
        #pragma unroll
        for (int k = 0; k < 128; ++k) a += t[k] * Wc[k * 10 + j];
        out[j] = a;
    }
}

// ---------------- launch ----------------
extern "C" void kernel_launch(void* const* d_in, const int* in_sizes, int n_in,
                              void* d_out, int out_size, void* d_ws, size_t ws_size,
                              hipStream_t stream) {
    (void)in_sizes; (void)n_in; (void)out_size; (void)ws_size;
    const float* x     = (const float*)d_in[0];
    const int*   ei    = (const int*)d_in[1];
    const int*   nord  = (const int*)d_in[2];
    const float* W_in  = (const float*)d_in[3];
    const float* b_in  = (const float*)d_in[4];
    const float* Wg1   = (const float*)d_in[5];
    const float* as1   = (const float*)d_in[6];
    const float* ad1   = (const float*)d_in[7];
    const float* bg1   = (const float*)d_in[8];
    const float* Wg2   = (const float*)d_in[9];
    const float* as2   = (const float*)d_in[10];
    const float* ad2   = (const float*)d_in[11];
    const float* bg2   = (const float*)d_in[12];
    const float* W_emb = (const float*)d_in[13];
    const float* b_emb = (const float*)d_in[14];
    const float* clst  = (const float*)d_in[15];
    const float* ln1s  = (const float*)d_in[16];
    const float* ln1b  = (const float*)d_in[17];
    const float* Wqkv  = (const float*)d_in[18];
    const float* bqkv  = (const float*)d_in[19];
    const float* Wo    = (const float*)d_in[20];
    const float* bo    = (const float*)d_in[21];
    const float* ln2s  = (const float*)d_in[22];
    const float* ln2b  = (const float*)d_in[23];
    const float* Wf1   = (const float*)d_in[24];
    const float* bf1   = (const float*)d_in[25];
    const float* Wf2   = (const float*)d_in[26];
    const float* bf2   = (const float*)d_in[27];
    const float* Wc    = (const float*)d_in[28];
    const float* bc    = (const float*)d_in[29];

    char* w = (char*)d_ws;
    size_t o = 0;
    auto ALLOC = [&](size_t nbytes) -> char* {
        char* p = w + o;
        o += (nbytes + 255) & ~(size_t)255;
        return p;
    };
    int*   cnt   = (int*)ALLOC((size_t)NN * 4);
    int*   fill  = (int*)ALLOC((size_t)NN * 4);   // contiguous with cnt
    int*   offs  = (int*)ALLOC((size_t)(NN + 1) * 4);
    int*   csr   = (int*)ALLOC((size_t)EN_TOT * 4);
    float* hA    = (float*)ALLOC((size_t)NN * 128 * 4);   // GAT2 output
    float* hW    = (float*)ALLOC((size_t)NN * 128 * 4);   // also pbuf
    float* h1    = (float*)ALLOC((size_t)NN * 128 * 4);
    float* ssrc  = (float*)ALLOC((size_t)NN * 4);
    float* sdst  = (float*)ALLOC((size_t)NN * 4);
    float* tbuf  = (float*)ALLOC((size_t)SS * 128 * 4);
    float* qkvb  = (float*)ALLOC((size_t)SS * 384 * 4);
    float* aob   = (float*)ALLOC((size_t)SS * 128 * 4);
    float* Wcomb = (float*)ALLOC((size_t)128 * 128 * 4);
    float* bcomb = (float*)ALLOC((size_t)128 * 4);
    float* pbuf  = hW;

    dim3 blk(256);
    int egrid = (EN_TOT + 255) / 256;

    // CSR by dst
    hipMemsetAsync(cnt, 0, (size_t)NN * 8, stream);
    hist_kernel<<<egrid, blk, 0, stream>>>(ei, cnt);
    scan_kernel<<<1, 1024, 0, stream>>>(cnt, offs);
    scatter_kernel<<<egrid, blk, 0, stream>>>(ei, offs, fill, csr);

    // Wcomb = W_in@Wg1 ; bcomb = b_in@Wg1
    gemm_f32<<<dim3(2, 2), blk, 0, stream>>>(W_in, Wg1, nullptr, nullptr, Wcomb, 128, 128, 128);
    bcomb_kernel<<<1, 128, 0, stream>>>(b_in, Wg1, bcomb);

    // GAT 1
    gemm_f32<<<dim3(2, 512), blk, 0, stream>>>(x, Wcomb, bcomb, nullptr, hW, NN, 128, 128);
    dots_kernel<<<8192, blk, 0, stream>>>(hW, as1, ad1, ssrc, sdst);
    gat_aggregate<<<8192, blk, 0, stream>>>(hW, offs, csr, ssrc, sdst, bg1, h1);
    // GAT 2
    gemm_f32<<<dim3(2, 512), blk, 0, stream>>>(h1, Wg2, nullptr, nullptr, hW, NN, 128, 128);
    dots_kernel<<<8192, blk, 0, stream>>>(hW, as2, ad2, ssrc, sdst);
    gat_aggregate<<<8192, blk, 0, stream>>>(hW, offs, csr, ssrc, sdst, bg2, hA);

    // tokens
    cls_copy<<<1, 128, 0, stream>>>(clst, tbuf);
    emb_gemm<<<dim3(2, 16, SPLIT), blk, 0, stream>>>(hA, W_emb, nord, pbuf);
    emb_reduce<<<512, blk, 0, stream>>>(pbuf, b_emb, tbuf + 128);

    for (int l = 0; l < LL; ++l) {
        fused_ln_qkv<<<257, blk, 0, stream>>>(tbuf, ln1s + l * 128, ln1b + l * 128,
                                              Wqkv + (size_t)l * 128 * 384, bqkv + l * 384, qkvb);
        attn_kernel<<<dim3(65, 8), blk, 0, stream>>>(qkvb, aob);
        fused_proj_ffn<<<257, blk, 0, stream>>>(aob, Wo + (size_t)l * 128 * 128, bo + l * 128,
                                                ln2s + l * 128, ln2b + l * 128,
                                                Wf1 + (size_t)l * 128 * 512, bf1 + l * 512,
                                                Wf2 + (size_t)l * 512 * 128, bf2 + l * 128, tbuf);
    }
    classifier_kernel<<<1, 64, 0, stream>>>(tbuf, Wc, bc, (float*)d_out);
}

// Round 4
// 874.244 us; speedup vs baseline: 1.7936x; 1.2102x over previous
//
#include <hip/hip_runtime.h>
#include <hip/hip_bf16.h>
#include <math.h>

#define NN 32768       // nodes
#define NE 524288      // edges
#define EN_TOT (NE + NN)
#define LL 8
#define SS 1025        // tokens (K+1)
#define SPLIT 16       // split-K for embedding gemm

// ---------------- CSR build ----------------
__global__ void hist_kernel(const int* __restrict__ ei, int* __restrict__ cnt) {
    int i = blockIdx.x * 256 + threadIdx.x;
    if (i >= EN_TOT) return;
    int d = (i < NE) ? ei[NE + i] : (i - NE);
    atomicAdd(&cnt[d], 1);
}

__global__ void scan_kernel(const int* __restrict__ cnt, int* __restrict__ offs) {
    __shared__ int wsum[16];
    int t = threadIdx.x;              // 0..1023, each owns 32 elements
    int base = t * 32;
    int s = 0;
    #pragma unroll
    for (int j = 0; j < 32; ++j) s += cnt[base + j];
    int lane = t & 63, w = t >> 6;
    int v = s;
    #pragma unroll
    for (int d = 1; d < 64; d <<= 1) {
        int u = __shfl_up(v, d);
        if (lane >= d) v += u;
    }
    if (lane == 63) wsum[w] = v;
    __syncthreads();
    if (t == 0) {
        int a = 0;
        #pragma unroll
        for (int i = 0; i < 16; ++i) { int x = wsum[i]; wsum[i] = a; a += x; }
    }
    __syncthreads();
    int run = wsum[w] + (v - s);
    #pragma unroll
    for (int j = 0; j < 32; ++j) { offs[base + j] = run; run += cnt[base + j]; }
    if (t == 1023) offs[NN] = run;
}

__global__ void scatter_kernel(const int* __restrict__ ei, const int* __restrict__ offs,
                               int* __restrict__ fill, int* __restrict__ csr) {
    int i = blockIdx.x * 256 + threadIdx.x;
    if (i >= EN_TOT) return;
    int s, d;
    if (i < NE) { s = ei[i]; d = ei[NE + i]; } else { s = d = i - NE; }
    int pos = offs[d] + atomicAdd(&fill[d], 1);
    csr[pos] = s;
}

// ---------------- generic fp32 GEMM (+opt bf16 copy, +opt fused GAT dots) ----------------
__device__ __forceinline__ float gelu_f(float x) {
    float x3 = x * x * x;
    return 0.5f * x * (1.f + tanhf(0.7978845608028654f * (x + 0.044715f * x3)));
}

__global__ void gemm_f32(const float* __restrict__ A, const float* __restrict__ B,
                         const float* __restrict__ bias, const float* res,
                         float* C, __hip_bfloat16* Cb,
                         const float* __restrict__ asv, const float* __restrict__ adv,
                         float* ssv, float* sdv,
                         int M, int Nn, int K) {
    __shared__ float As[32][66];
    __shared__ float Bs[32][72];
    int t = threadIdx.x;
    int bx = blockIdx.x, by = blockIdx.y;
    int tx = t & 15, ty = t >> 4;
    float acc[4][4] = {};
    int m0 = t >> 3;
    int kk4 = (t & 7) * 4;
    int kb0 = t >> 4;
    int n40 = (t & 15) * 4;

    for (int k0 = 0; k0 < K; k0 += 32) {
        __syncthreads();
        #pragma unroll
        for (int half = 0; half < 2; ++half) {
            int m = m0 + half * 32;
            int row = by * 64 + m;
            float4 v = {0.f, 0.f, 0.f, 0.f};
            if (row < M) v = *(const float4*)&A[(size_t)row * K + k0 + kk4];
            As[kk4 + 0][m] = v.x; As[kk4 + 1][m] = v.y;
            As[kk4 + 2][m] = v.z; As[kk4 + 3][m] = v.w;
        }
        #pragma unroll
        for (int half = 0; half < 2; ++half) {
            int kk = kb0 + half * 16;
            *(float4*)&Bs[kk][n40] = *(const float4*)&B[(size_t)(k0 + kk) * Nn + bx * 64 + n40];
        }
        __syncthreads();
        #pragma unroll
        for (int kk = 0; kk < 32; ++kk) {
            float a0 = As[kk][ty * 4 + 0];
            float a1 = As[kk][ty * 4 + 1];
            float a2 = As[kk][ty * 4 + 2];
            float a3 = As[kk][ty * 4 + 3];
            float4 b4 = *(float4*)&Bs[kk][tx * 4];
            acc[0][0] += a0 * b4.x; acc[0][1] += a0 * b4.y; acc[0][2] += a0 * b4.z; acc[0][3] += a0 * b4.w;
            acc[1][0] += a1 * b4.x; acc[1][1] += a1 * b4.y; acc[1][2] += a1 * b4.z; acc[1][3] += a1 * b4.w;
            acc[2][0] += a2 * b4.x; acc[2][1] += a2 * b4.y; acc[2][2] += a2 * b4.z; acc[2][3] += a2 * b4.w;
            acc[3][0] += a3 * b4.x; acc[3][1] += a3 * b4.y; acc[3][2] += a3 * b4.z; acc[3][3] += a3 * b4.w;
        }
    }
    #pragma unroll
    for (int i = 0; i < 4; ++i) {
        int row = by * 64 + ty * 4 + i;
        if (row < M) {
            #pragma unroll
            for (int j = 0; j < 4; ++j) {
                int col = bx * 64 + tx * 4 + j;
                float v = acc[i][j];
                if (bias) v += bias[col];
                if (res) v += res[(size_t)row * Nn + col];
                acc[i][j] = v;
                C[(size_t)row * Nn + col] = v;
                if (Cb) Cb[(size_t)row * Nn + col] = __float2bfloat16(v);
            }
        }
    }
    if (asv) {   // fused GAT attention dots: ssv[row] += h.asrc, sdv[row] += h.adst
        #pragma unroll
        for (int i = 0; i < 4; ++i) {
            int row = by * 64 + ty * 4 + i;
            float vs = 0.f, vd = 0.f;
            #pragma unroll
            for (int j = 0; j < 4; ++j) {
                int col = bx * 64 + tx * 4 + j;
                vs += acc[i][j] * asv[col];
                vd += acc[i][j] * adv[col];
            }
            #pragma unroll
            for (int m = 8; m >= 1; m >>= 1) { vs += __shfl_xor(vs, m); vd += __shfl_xor(vd, m); }
            if (tx == 0 && row < M) {
                atomicAdd(&ssv[row], vs);
                atomicAdd(&sdv[row], vd);
            }
        }
    }
}

__global__ void bcomb_kernel(const float* __restrict__ b_in, const float* __restrict__ Wg1,
                             float* __restrict__ bcomb) {
    int n = threadIdx.x;  // 128
    float s = 0.f;
    for (int k = 0; k < 128; ++k) s += b_in[k] * Wg1[k * 128 + n];
    bcomb[n] = s;
}

// ---------------- split-K gathered embedding GEMM ----------------
__global__ void emb_gemm(const float* __restrict__ h, const float* __restrict__ W,
                         const int* __restrict__ no, float* __restrict__ pbuf) {
    __shared__ float As[32][66];
    __shared__ float Bs[32][72];
    int t = threadIdx.x;
    int bx = blockIdx.x, by = blockIdx.y, sp = blockIdx.z;
    int tx = t & 15, ty = t >> 4;
    float acc[4][4] = {};
    int m0 = t >> 3;
    int kk4 = (t & 7) * 4;
    int kb0 = t >> 4;
    int n40 = (t & 15) * 4;
    int kbase = sp * 256;

    for (int k0 = 0; k0 < 256; k0 += 32) {
        __syncthreads();
        #pragma unroll
        for (int half = 0; half < 2; ++half) {
            int m = m0 + half * 32;
            int row = by * 64 + m;
            int kg = kbase + k0 + kk4;
            int node = no[row * 32 + (kg >> 7)];
            float4 v = *(const float4*)&h[(size_t)node * 128 + (kg & 127)];
            As[kk4 + 0][m] = v.x; As[kk4 + 1][m] = v.y;
            As[kk4 + 2][m] = v.z; As[kk4 + 3][m] = v.w;
        }
        #pragma unroll
        for (int half = 0; half < 2; ++half) {
            int kk = kb0 + half * 16;
            *(float4*)&Bs[kk][n40] = *(const float4*)&W[(size_t)(kbase + k0 + kk) * 128 + bx * 64 + n40];
        }
        __syncthreads();
        #pragma unroll
        for (int kk = 0; kk < 32; ++kk) {
            float a0 = As[kk][ty * 4 + 0];
            float a1 = As[kk][ty * 4 + 1];
            float a2 = As[kk][ty * 4 + 2];
            float a3 = As[kk][ty * 4 + 3];
            float4 b4 = *(float4*)&Bs[kk][tx * 4];
            acc[0][0] += a0 * b4.x; acc[0][1] += a0 * b4.y; acc[0][2] += a0 * b4.z; acc[0][3] += a0 * b4.w;
            acc[1][0] += a1 * b4.x; acc[1][1] += a1 * b4.y; acc[1][2] += a1 * b4.z; acc[1][3] += a1 * b4.w;
            acc[2][0] += a2 * b4.x; acc[2][1] += a2 * b4.y; acc[2][2] += a2 * b4.z; acc[2][3] += a2 * b4.w;
            acc[3][0] += a3 * b4.x; acc[3][1] += a3 * b4.y; acc[3][2] += a3 * b4.z; acc[3][3] += a3 * b4.w;
        }
    }
    float* C = pbuf + (size_t)sp * (1024 * 128);
    #pragma unroll
    for (int i = 0; i < 4; ++i) {
        int row = by * 64 + ty * 4 + i;
        #pragma unroll
        for (int j = 0; j < 4; ++j)
            C[(size_t)row * 128 + bx * 64 + tx * 4 + j] = acc[i][j];
    }
}

__global__ void emb_reduce(const float* __restrict__ pbuf, const float* __restrict__ b_emb,
                           float* __restrict__ out) {
    int i = blockIdx.x * 256 + threadIdx.x;   // 0..131071
    float s = b_emb[i & 127];
    #pragma unroll
    for (int sp = 0; sp < SPLIT; ++sp) s += pbuf[(size_t)sp * 131072 + i];
    out[i] = s;
}

// ---------------- GAT aggregation (bf16 gather) ----------------
// hWb: [NN][128] bf16 packed as uint pairs; lane owns dims {2*lane, 2*lane+1}
__global__ void gat_aggregate(const unsigned* __restrict__ hWb, const int* __restrict__ offs,
                              const int* __restrict__ csr, const float* __restrict__ ssrc,
                              const float* __restrict__ sdst, const float* __restrict__ bias,
                              float* __restrict__ out) {
    int lane = threadIdx.x & 63;
    int n = blockIdx.x * 4 + (threadIdx.x >> 6);
    int beg = offs[n], end = offs[n + 1];
    float sd = sdst[n];
    float mymax = -INFINITY;
    for (int p = beg + lane; p < end; p += 64) {
        float e = ssrc[csr[p]] + sd;
        e = (e >= 0.f) ? e : 0.2f * e;
        mymax = fmaxf(mymax, e);
    }
    #pragma unroll
    for (int m = 32; m >= 1; m >>= 1) mymax = fmaxf(mymax, __shfl_xor(mymax, m));
    float mysum = 0.f;
    for (int p = beg + lane; p < end; p += 64) {
        float e = ssrc[csr[p]] + sd;
        e = (e >= 0.f) ? e : 0.2f * e;
        mysum += __expf(e - mymax);
    }
    #pragma unroll
    for (int m = 32; m >= 1; m >>= 1) mysum += __shfl_xor(mysum, m);
    float inv = 1.f / mysum;
    float acc0 = 0.f, acc1 = 0.f;
    for (int p = beg; p < end; ++p) {
        int s = csr[p];
        float e = ssrc[s] + sd;
        e = (e >= 0.f) ? e : 0.2f * e;
        float al = __expf(e - mymax) * inv;
        unsigned u = hWb[(size_t)s * 64 + lane];       // 2 bf16 = dims 2*lane, 2*lane+1
        float f0 = __uint_as_float(u << 16);
        float f1 = __uint_as_float(u & 0xffff0000u);
        acc0 += al * f0;
        acc1 += al * f1;
    }
    float2 ov;
    ov.x = acc0 + bias[2 * lane];
    ov.y = acc1 + bias[2 * lane + 1];
    *(float2*)&out[(size_t)n * 128 + 2 * lane] = ov;
}

// ---------------- transformer kernels ----------------
// QKV col-slice: grid (257, 3). u = LN1(t) (recomputed per slice); qkv[:, s*128:+128] = u@Wq_s + bq_s
__global__ __launch_bounds__(256) void qkv_slice(
        const float* __restrict__ tb, const float* __restrict__ s1, const float* __restrict__ b1,
        const float* __restrict__ Wq, const float* __restrict__ bq, float* __restrict__ qkv) {
    __shared__ float u[4][128];
    __shared__ float red[4][2][128];
    __shared__ float ws[8192];   // 32 KB: 64 k-rows x 128 cols
    int t = threadIdx.x;
    int r0 = blockIdx.x * 4, sl = blockIdx.y;
    int col = t & 127, kh = t >> 7;
    {   // LN1: 64 lanes per row
        int rw = t >> 6, lane = t & 63;
        int row = r0 + rw;
        float a0 = 0.f, a1 = 0.f;
        if (row < SS) {
            a0 = tb[(size_t)row * 128 + lane];
            a1 = tb[(size_t)row * 128 + 64 + lane];
        }
        float sm = a0 + a1;
        #pragma unroll
        for (int m = 32; m >= 1; m >>= 1) sm += __shfl_xor(sm, m);
        float mean = sm * (1.f / 128.f);
        float d0 = a0 - mean, d1 = a1 - mean;
        float vv = d0 * d0 + d1 * d1;
        #pragma unroll
        for (int m = 32; m >= 1; m >>= 1) vv += __shfl_xor(vv, m);
        float rs = rsqrtf(vv * (1.f / 128.f) + 1e-5f);
        u[rw][lane] = d0 * rs * s1[lane] + b1[lane];
        u[rw][64 + lane] = d1 * rs * s1[64 + lane] + b1[64 + lane];
    }
    float acc[4] = {};
    for (int k0 = 0; k0 < 128; k0 += 64) {
        __syncthreads();
        const float* src = Wq + (size_t)k0 * 384 + sl * 128;
        #pragma unroll
        for (int i = 0; i < 8; ++i) {
            int idx = i * 256 + t;          // float4 index, 32 per k-row
            int kk = idx >> 5, c4 = (idx & 31) * 4;
            ((float4*)ws)[idx] = *(const float4*)&src[(size_t)kk * 384 + c4];
        }
        __syncthreads();
        int kb = kh * 32;
        #pragma unroll
        for (int kq = 0; kq < 32; kq += 4) {
            float a4[4][4];
            #pragma unroll
            for (int i = 0; i < 4; ++i)
                *(float4*)a4[i] = *(const float4*)&u[i][k0 + kb + kq];
            #pragma unroll
            for (int q = 0; q < 4; ++q) {
                float b = ws[(kb + kq + q) * 128 + col];
                #pragma unroll
                for (int i = 0; i < 4; ++i) acc[i] += a4[i][q] * b;
            }
        }
    }
    __syncthreads();
    #pragma unroll
    for (int i = 0; i < 4; ++i) red[i][kh][col] = acc[i];
    __syncthreads();
    if (t < 128) {
        float bqv = bq[sl * 128 + t];
        #pragma unroll
        for (int i = 0; i < 4; ++i) {
            int row = r0 + i;
            if (row < SS)
                qkv[(size_t)row * 384 + sl * 128 + t] = red[i][0][t] + red[i][1][t] + bqv;
        }
    }
}

// proj + residual + LN2: tn = o@Wo + bo + t; tb = tn + bf2 (FFN partials atomicAdd later); ub = LN2(tn)
__global__ __launch_bounds__(256) void proj_ln2(
        const float* __restrict__ ao, const float* __restrict__ Wo, const float* __restrict__ bo,
        const float* __restrict__ s2, const float* __restrict__ b2, const float* __restrict__ bf2,
        float* __restrict__ tb, float* __restrict__ ub) {
    __shared__ float bufA[4][128];
    __shared__ float tn[4][128];
    __shared__ float red[4][2][128];
    __shared__ float ws[8192];
    int t = threadIdx.x;
    int r0 = blockIdx.x * 4;
    int lane = t & 63;
    int col = t & 127, kh = t >> 7;
    {   // stage o rows
        int rw = t >> 6;
        int row = r0 + rw;
        float a0 = 0.f, a1 = 0.f;
        if (row < SS) {
            a0 = ao[(size_t)row * 128 + lane];
            a1 = ao[(size_t)row * 128 + 64 + lane];
        }
        bufA[rw][lane] = a0;
        bufA[rw][64 + lane] = a1;
    }
    float pp[4] = {};
    for (int k0 = 0; k0 < 128; k0 += 64) {
        __syncthreads();
        const float4* src = (const float4*)&Wo[(size_t)k0 * 128];
        #pragma unroll
        for (int i = 0; i < 8; ++i) ((float4*)ws)[i * 256 + t] = src[i * 256 + t];
        __syncthreads();
        int kb = kh * 32;
        #pragma unroll
        for (int kq = 0; kq < 32; kq += 4) {
            float a4[4][4];
            #pragma unroll
            for (int i = 0; i < 4; ++i)
                *(float4*)a4[i] = *(const float4*)&bufA[i][k0 + kb + kq];
            #pragma unroll
            for (int q = 0; q < 4; ++q) {
                float b = ws[(kb + kq + q) * 128 + col];
                #pragma unroll
                for (int i = 0; i < 4; ++i) pp[i] += a4[i][q] * b;
            }
        }
    }
    __syncthreads();
    #pragma unroll
    for (int i = 0; i < 4; ++i) red[i][kh][col] = pp[i];
    __syncthreads();
    if (t < 128) {
        #pragma unroll
        for (int i = 0; i < 4; ++i) {
            int row = r0 + i;
            float v = 0.f;
            if (row < SS) {
                v = red[i][0][t] + red[i][1][t] + bo[t] + tb[(size_t)row * 128 + t];
                tb[(size_t)row * 128 + t] = v + bf2[t];   // FFN partials accumulate on top
            }
            tn[i][t] = v;
        }
    }
    __syncthreads();
    {   // LN2(tn) -> ub
        int rw = t >> 6;
        int row = r0 + rw;
        float a0 = tn[rw][lane], a1 = tn[rw][64 + lane];
        float sm = a0 + a1;
        #pragma unroll
        for (int m = 32; m >= 1; m >>= 1) sm += __shfl_xor(sm, m);
        float mean = sm * (1.f / 128.f);
        float d0 = a0 - mean, d1 = a1 - mean;
        float vv = d0 * d0 + d1 * d1;
        #pragma unroll
        for (int m = 32; m >= 1; m >>= 1) vv += __shfl_xor(vv, m);
        float rs = rsqrtf(vv * (1.f / 128.f) + 1e-5f);
        if (row < SS) {
            ub[(size_t)row * 128 + lane] = d0 * rs * s2[lane] + b2[lane];
            ub[(size_t)row * 128 + 64 + lane] = d1 * rs * s2[64 + lane] + b2[64 + lane];
        }
    }
}

// FFN hidden-slice: grid (257, 4). g = gelu(u@Wf1[:,sl]+bf1[sl]); tb += g@Wf2[sl,:]
__global__ __launch_bounds__(256) void ffn_part(
        const float* __restrict__ ub, const float* __restrict__ Wf1, const float* __restrict__ bf1,
        const float* __restrict__ Wf2, float* __restrict__ tb) {
    __shared__ float u[4][128];
    __shared__ float g[4][128];
    __shared__ float red[4][2][128];
    __shared__ float ws[8192];
    int t = threadIdx.x;
    int r0 = blockIdx.x * 4, sl = blockIdx.y;
    int col = t & 127, kh = t >> 7;
    {   // load u rows
        int rw = t >> 6, lane = t & 63;
        int row = r0 + rw;
        float a0 = 0.f, a1 = 0.f;
        if (row < SS) {
            a0 = ub[(size_t)row * 128 + lane];
            a1 = ub[(size_t)row * 128 + 64 + lane];
        }
        u[rw][lane] = a0;
        u[rw][64 + lane] = a1;
    }
    // ffn1 slice
    float a1c[4] = {};
    for (int k0 = 0; k0 < 128; k0 += 64) {
        __syncthreads();
        const float* src = Wf1 + (size_t)k0 * 512 + sl * 128;
        #pragma unroll
        for (int i = 0; i < 8; ++i) {
            int idx = i * 256 + t;
            int kk = idx >> 5, c4 = (idx & 31) * 4;
            ((float4*)ws)[idx] = *(const float4*)&src[(size_t)kk * 512 + c4];
        }
        __syncthreads();
        int kb = kh * 32;
        #pragma unroll
        for (int kq = 0; kq < 32; kq += 4) {
            float a4[4][4];
            #pragma unroll
            for (int i = 0; i < 4; ++i)
                *(float4*)a4[i] = *(const float4*)&u[i][k0 + kb + kq];
            #pragma unroll
            for (int q = 0; q < 4; ++q) {
                float b = ws[(kb + kq + q) * 128 + col];
                #pragma unroll
                for (int i = 0; i < 4; ++i) a1c[i] += a4[i][q] * b;
            }
        }
    }
    __syncthreads();
    #pragma unroll
    for (int i = 0; i < 4; ++i) red[i][kh][col] = a1c[i];
    __syncthreads();
    if (t < 128) {
        float bv = bf1[sl * 128 + t];
        #pragma unroll
        for (int i = 0; i < 4; ++i)
            g[i][t] = gelu_f(red[i][0][t] + red[i][1][t] + bv);
    }
    // ffn2 slice: Wf2 rows [sl*128, sl*128+128) are contiguous
    float a2c[4] = {};
    for (int k0 = 0; k0 < 128; k0 += 64) {
        __syncthreads();
        const float4* src = (const float4*)&Wf2[(size_t)(sl * 128 + k0) * 128];
        #pragma unroll
        for (int i = 0; i < 8; ++i) ((float4*)ws)[i * 256 + t] = src[i * 256 + t];
        __syncthreads();
        int kb = kh * 32;
        #pragma unroll
        for (int kq = 0; kq < 32; kq += 4) {
            float a4[4][4];
            #pragma unroll
            for (int i = 0; i < 4; ++i)
                *(float4*)a4[i] = *(const float4*)&g[i][k0 + kb + kq];
            #pragma unroll
            for (int q = 0; q < 4; ++q) {
                float b = ws[(kb + kq + q) * 128 + col];
                #pragma unroll
                for (int i = 0; i < 4; ++i) a2c[i] += a4[i][q] * b;
            }
        }
    }
    __syncthreads();
    #pragma unroll
    for (int i = 0; i < 4; ++i) red[i][kh][col] = a2c[i];
    __syncthreads();
    if (t < 128) {
        #pragma unroll
        for (int i = 0; i < 4; ++i) {
            int row = r0 + i;
            if (row < SS)
                atomicAdd(&tb[(size_t)row * 128 + t], red[i][0][t] + red[i][1][t]);
        }
    }
}

// flash attention: dh=16, 16 lanes per query row, K/V tiles (64 keys) in LDS
__global__ void attn_kernel(const float* __restrict__ qkv, float* __restrict__ ao) {
    __shared__ float Kl[64][20];
    __shared__ float Vl[64][20];
    int h = blockIdx.y;
    int t = threadIdx.x;
    int sub = t & 15;
    int qr = blockIdx.x * 16 + (t >> 4);
    bool active = qr < SS;
    float q[16];
    if (active) {
        #pragma unroll
        for (int d = 0; d < 16; ++d) q[d] = qkv[(size_t)qr * 384 + h * 16 + d];
    }
    float m = -INFINITY, sum = 0.f;
    float acc[16] = {};
    for (int j0 = 0; j0 < SS; j0 += 64) {
        __syncthreads();
        int j = t >> 2, dg = (t & 3) * 4;
        if (j0 + j < SS) {
            const float* row = qkv + (size_t)(j0 + j) * 384 + h * 16 + dg;
            *(float4*)&Kl[j][dg] = *(const float4*)(row + 128);
            *(float4*)&Vl[j][dg] = *(const float4*)(row + 256);
        }
        __syncthreads();
        if (active) {
            int jmax = min(64, SS - j0);
            for (int jj = sub; jj < jmax; jj += 16) {
                float4 ka = *(const float4*)&Kl[jj][0];
                float4 kb = *(const float4*)&Kl[jj][4];
                float4 kc = *(const float4*)&Kl[jj][8];
                float4 kd = *(const float4*)&Kl[jj][12];
                float sc = q[0]*ka.x + q[1]*ka.y + q[2]*ka.z + q[3]*ka.w
                         + q[4]*kb.x + q[5]*kb.y + q[6]*kb.z + q[7]*kb.w
                         + q[8]*kc.x + q[9]*kc.y + q[10]*kc.z + q[11]*kc.w
                         + q[12]*kd.x + q[13]*kd.y + q[14]*kd.z + q[15]*kd.w;
                sc *= 0.25f;
                float4 va = *(const float4*)&Vl[jj][0];
                float4 vb = *(const float4*)&Vl[jj][4];
                float4 vc = *(const float4*)&Vl[jj][8];
                float4 vd = *(const float4*)&Vl[jj][12];
                float vv[16] = {va.x, va.y, va.z, va.w, vb.x, vb.y, vb.z, vb.w,
                                vc.x, vc.y, vc.z, vc.w, vd.x, vd.y, vd.z, vd.w};
                if (sc <= m) {
                    float p = __expf(sc - m);
                    sum += p;
                    #pragma unroll
                    for (int d = 0; d < 16; ++d) acc[d] += p * vv[d];
                } else {
                    float c = __expf(m - sc);
                    sum = sum * c + 1.f;
                    #pragma unroll
                    for (int d = 0; d < 16; ++d) acc[d] = acc[d] * c + vv[d];
                    m = sc;
                }
            }
        }
    }
    if (active) {
        #pragma unroll
        for (int msk = 1; msk < 16; msk <<= 1) {
            float mo = __shfl_xor(m, msk);
            float so = __shfl_xor(sum, msk);
            float vo[16];
            #pragma unroll
            for (int d = 0; d < 16; ++d) vo[d] = __shfl_xor(acc[d], msk);
            float mn = fmaxf(m, mo);
            float c1 = __expf(m - mn), c2 = __expf(mo - mn);
            sum = sum * c1 + so * c2;
            #pragma unroll
            for (int d = 0; d < 16; ++d) acc[d] = acc[d] * c1 + vo[d] * c2;
            m = mn;
        }
        if (sub == 0) {
            float inv = 1.f / sum;
            #pragma unroll
            for (int d = 0; d < 16; ++d) ao[(size_t)qr * 128 + h * 16 + d] = acc[d] * inv;
        }
    }
}

__global__ void cls_copy(const float* __restrict__ c, float* __restrict__ t) {
    t[threadIdx.x] = c[threadIdx.x];
}

__global__ void classifier_kernel(const float* __restrict__ t, const float* __restrict__ Wc,
                                  const float* __restrict__ bc, float* __restrict__ out) {
    int j = threadIdx.x;
    if (j < 10) {
        float a = bc[j];
        #pragma unroll
        for (int k = 0; k < 128; ++k) a += t[k] * Wc[k * 10 + j];
        out[j] = a;
    }
}

// ---------------- launch ----------------
extern "C" void kernel_launch(void* const* d_in, const int* in_sizes, int n_in,
                              void* d_out, int out_size, void* d_ws, size_t ws_size,
                              hipStream_t stream) {
    (void)in_sizes; (void)n_in; (void)out_size; (void)ws_size;
    const float* x     = (const float*)d_in[0];
    const int*   ei    = (const int*)d_in[1];
    const int*   nord  = (const int*)d_in[2];
    const float* W_in  = (const float*)d_in[3];
    const float* b_in  = (const float*)d_in[4];
    const float* Wg1   = (const float*)d_in[5];
    const float* as1   = (const float*)d_in[6];
    const float* ad1   = (const float*)d_in[7];
    const float* bg1   = (const float*)d_in[8];
    const float* Wg2   = (const float*)d_in[9];
    const float* as2   = (const float*)d_in[10];
    const float* ad2   = (const float*)d_in[11];
    const float* bg2   = (const float*)d_in[12];
    const float* W_emb = (const float*)d_in[13];
    const float* b_emb = (const float*)d_in[14];
    const float* clst  = (const float*)d_in[15];
    const float* ln1s  = (const float*)d_in[16];
    const float* ln1b  = (const float*)d_in[17];
    const float* Wqkv  = (const float*)d_in[18];
    const float* bqkv  = (const float*)d_in[19];
    const float* Wo    = (const float*)d_in[20];
    const float* bo    = (const float*)d_in[21];
    const float* ln2s  = (const float*)d_in[22];
    const float* ln2b  = (const float*)d_in[23];
    const float* Wf1   = (const float*)d_in[24];
    const float* bf1   = (const float*)d_in[25];
    const float* Wf2   = (const float*)d_in[26];
    const float* bf2   = (const float*)d_in[27];
    const float* Wc    = (const float*)d_in[28];
    const float* bc    = (const float*)d_in[29];

    char* w = (char*)d_ws;
    size_t o = 0;
    auto ALLOC = [&](size_t nbytes) -> char* {
        char* p = w + o;
        o += (nbytes + 255) & ~(size_t)255;
        return p;
    };
    int*   cnt   = (int*)ALLOC((size_t)NN * 4);
    int*   fill  = (int*)ALLOC((size_t)NN * 4);            // contiguous with cnt
    int*   offs  = (int*)ALLOC((size_t)(NN + 1) * 4);
    int*   csr   = (int*)ALLOC((size_t)EN_TOT * 4);
    float* hA    = (float*)ALLOC((size_t)NN * 128 * 4);    // GAT2 output
    float* hW    = (float*)ALLOC((size_t)NN * 128 * 4);    // also pbuf
    float* h1    = (float*)ALLOC((size_t)NN * 128 * 4);
    __hip_bfloat16* hWb = (__hip_bfloat16*)ALLOC((size_t)NN * 128 * 2);
    float* ssrc  = (float*)ALLOC((size_t)NN * 4);
    float* sdst  = (float*)ALLOC((size_t)NN * 4);          // contiguous with ssrc
    float* tbuf  = (float*)ALLOC((size_t)SS * 128 * 4);
    float* ubuf  = (float*)ALLOC((size_t)SS * 128 * 4);
    float* qkvb  = (float*)ALLOC((size_t)SS * 384 * 4);
    float* aob   = (float*)ALLOC((size_t)SS * 128 * 4);
    float* Wcomb = (float*)ALLOC((size_t)128 * 128 * 4);
    float* bcomb = (float*)ALLOC((size_t)128 * 4);
    float* pbuf  = hW;

    dim3 blk(256);
    int egrid = (EN_TOT + 255) / 256;

    // CSR by dst
    hipMemsetAsync(cnt, 0, (size_t)NN * 8, stream);
    hist_kernel<<<egrid, blk, 0, stream>>>(ei, cnt);
    scan_kernel<<<1, 1024, 0, stream>>>(cnt, offs);
    scatter_kernel<<<egrid, blk, 0, stream>>>(ei, offs, fill, csr);

    // Wcomb = W_in@Wg1 ; bcomb = b_in@Wg1
    gemm_f32<<<dim3(2, 2), blk, 0, stream>>>(W_in, Wg1, nullptr, nullptr, Wcomb,
                                             nullptr, nullptr, nullptr, nullptr, nullptr,
                                             128, 128, 128);
    bcomb_kernel<<<1, 128, 0, stream>>>(b_in, Wg1, bcomb);

    // GAT 1: hW = x@Wcomb + bcomb (+ bf16 copy + fused dots)
    hipMemsetAsync(ssrc, 0, (size_t)NN * 8, stream);
    gemm_f32<<<dim3(2, 512), blk, 0, stream>>>(x, Wcomb, bcomb, nullptr, hW,
                                               hWb, as1, ad1, ssrc, sdst,
                                               NN, 128, 128);
    gat_aggregate<<<8192, blk, 0, stream>>>((const unsigned*)hWb, offs, csr, ssrc, sdst, bg1, h1);
    // GAT 2
    hipMemsetAsync(ssrc, 0, (size_t)NN * 8, stream);
    gemm_f32<<<dim3(2, 512), blk, 0, stream>>>(h1, Wg2, nullptr, nullptr, hW,
                                               hWb, as2, ad2, ssrc, sdst,
                                               NN, 128, 128);
    gat_aggregate<<<8192, blk, 0, stream>>>((const unsigned*)hWb, offs, csr, ssrc, sdst, bg2, hA);

    // tokens
    cls_copy<<<1, 128, 0, stream>>>(clst, tbuf);
    emb_gemm<<<dim3(2, 16, SPLIT), blk, 0, stream>>>(hA, W_emb, nord, pbuf);
    emb_reduce<<<512, blk, 0, stream>>>(pbuf, b_emb, tbuf + 128);

    for (int l = 0; l < LL; ++l) {
        qkv_slice<<<dim3(257, 3), blk, 0, stream>>>(tbuf, ln1s + l * 128, ln1b + l * 128,
                                                    Wqkv + (size_t)l * 128 * 384, bqkv + l * 384, qkvb);
        attn_kernel<<<dim3(65, 8), blk, 0, stream>>>(qkvb, aob);
        proj_ln2<<<257, blk, 0, stream>>>(aob, Wo + (size_t)l * 128 * 128, bo + l * 128,
                                          ln2s + l * 128, ln2b + l * 128, bf2 + l * 128,
                                          tbuf, ubuf);
        ffn_part<<<dim3(257, 4), blk, 0, stream>>>(ubuf, Wf1 + (size_t)l * 128 * 512, bf1 + l * 512,
                                                   Wf2 + (size_t)l * 512 * 128, tbuf);
    }
    classifier_kernel<<<1, 64, 0, stream>>>(tbuf, Wc, bc, (float*)d_out);
}

// Round 6
// 835.009 us; speedup vs baseline: 1.8779x; 1.0470x over previous
//
#include <hip/hip_runtime.h>
#include <hip/hip_bf16.h>
#include <math.h>

#define NN 32768       // nodes
#define NE 524288      // edges
#define EN_TOT (NE + NN)
#define LL 8
#define SS 1025        // tokens (K+1)
#define SPLIT 16       // split-K for embedding gemm

// ---------------- CSR build ----------------
__global__ void hist_kernel(const int* __restrict__ ei, int* __restrict__ cnt) {
    int i = blockIdx.x * 256 + threadIdx.x;
    if (i >= EN_TOT) return;
    int d = (i < NE) ? ei[NE + i] : (i - NE);
    atomicAdd(&cnt[d], 1);
}

__global__ void scan_kernel(const int* __restrict__ cnt, int* __restrict__ offs) {
    __shared__ int wsum[16];
    int t = threadIdx.x;              // 0..1023, each owns 32 elements
    int base = t * 32;
    int s = 0;
    #pragma unroll
    for (int j = 0; j < 32; ++j) s += cnt[base + j];
    int lane = t & 63, w = t >> 6;
    int v = s;
    #pragma unroll
    for (int d = 1; d < 64; d <<= 1) {
        int u = __shfl_up(v, d);
        if (lane >= d) v += u;
    }
    if (lane == 63) wsum[w] = v;
    __syncthreads();
    if (t == 0) {
        int a = 0;
        #pragma unroll
        for (int i = 0; i < 16; ++i) { int x = wsum[i]; wsum[i] = a; a += x; }
    }
    __syncthreads();
    int run = wsum[w] + (v - s);
    #pragma unroll
    for (int j = 0; j < 32; ++j) { offs[base + j] = run; run += cnt[base + j]; }
    if (t == 1023) offs[NN] = run;
}

__global__ void scatter_kernel(const int* __restrict__ ei, const int* __restrict__ offs,
                               int* __restrict__ fill, int* __restrict__ csr) {
    int i = blockIdx.x * 256 + threadIdx.x;
    if (i >= EN_TOT) return;
    int s, d;
    if (i < NE) { s = ei[i]; d = ei[NE + i]; } else { s = d = i - NE; }
    int pos = offs[d] + atomicAdd(&fill[d], 1);
    csr[pos] = s;
}

// ---------------- generic fp32 GEMM (+opt fused GAT dots) ----------------
__device__ __forceinline__ float gelu_f(float x) {
    float x3 = x * x * x;
    return 0.5f * x * (1.f + tanhf(0.7978845608028654f * (x + 0.044715f * x3)));
}

__global__ void gemm_f32(const float* __restrict__ A, const float* __restrict__ B,
                         const float* __restrict__ bias, const float* res,
                         float* C,
                         const float* __restrict__ asv, const float* __restrict__ adv,
                         float* ssv, float* sdv,
                         int M, int Nn, int K) {
    __shared__ float As[32][66];
    __shared__ float Bs[32][72];
    int t = threadIdx.x;
    int bx = blockIdx.x, by = blockIdx.y;
    int tx = t & 15, ty = t >> 4;
    float acc[4][4] = {};
    int m0 = t >> 3;
    int kk4 = (t & 7) * 4;
    int kb0 = t >> 4;
    int n40 = (t & 15) * 4;

    for (int k0 = 0; k0 < K; k0 += 32) {
        __syncthreads();
        #pragma unroll
        for (int half = 0; half < 2; ++half) {
            int m = m0 + half * 32;
            int row = by * 64 + m;
            float4 v = {0.f, 0.f, 0.f, 0.f};
            if (row < M) v = *(const float4*)&A[(size_t)row * K + k0 + kk4];
            As[kk4 + 0][m] = v.x; As[kk4 + 1][m] = v.y;
            As[kk4 + 2][m] = v.z; As[kk4 + 3][m] = v.w;
        }
        #pragma unroll
        for (int half = 0; half < 2; ++half) {
            int kk = kb0 + half * 16;
            *(float4*)&Bs[kk][n40] = *(const float4*)&B[(size_t)(k0 + kk) * Nn + bx * 64 + n40];
        }
        __syncthreads();
        #pragma unroll
        for (int kk = 0; kk < 32; ++kk) {
            float a0 = As[kk][ty * 4 + 0];
            float a1 = As[kk][ty * 4 + 1];
            float a2 = As[kk][ty * 4 + 2];
            float a3 = As[kk][ty * 4 + 3];
            float4 b4 = *(float4*)&Bs[kk][tx * 4];
            acc[0][0] += a0 * b4.x; acc[0][1] += a0 * b4.y; acc[0][2] += a0 * b4.z; acc[0][3] += a0 * b4.w;
            acc[1][0] += a1 * b4.x; acc[1][1] += a1 * b4.y; acc[1][2] += a1 * b4.z; acc[1][3] += a1 * b4.w;
            acc[2][0] += a2 * b4.x; acc[2][1] += a2 * b4.y; acc[2][2] += a2 * b4.z; acc[2][3] += a2 * b4.w;
            acc[3][0] += a3 * b4.x; acc[3][1] += a3 * b4.y; acc[3][2] += a3 * b4.z; acc[3][3] += a3 * b4.w;
        }
    }
    #pragma unroll
    for (int i = 0; i < 4; ++i) {
        int row = by * 64 + ty * 4 + i;
        if (row < M) {
            #pragma unroll
            for (int j = 0; j < 4; ++j) {
                int col = bx * 64 + tx * 4 + j;
                float v = acc[i][j];
                if (bias) v += bias[col];
                if (res) v += res[(size_t)row * Nn + col];
                acc[i][j] = v;
                C[(size_t)row * Nn + col] = v;
            }
        }
    }
    if (asv) {   // fused GAT attention dots: ssv[row] += h.asrc, sdv[row] += h.adst
        #pragma unroll
        for (int i = 0; i < 4; ++i) {
            int row = by * 64 + ty * 4 + i;
            float vs = 0.f, vd = 0.f;
            #pragma unroll
            for (int j = 0; j < 4; ++j) {
                int col = bx * 64 + tx * 4 + j;
                vs += acc[i][j] * asv[col];
                vd += acc[i][j] * adv[col];
            }
            #pragma unroll
            for (int m = 8; m >= 1; m >>= 1) { vs += __shfl_xor(vs, m); vd += __shfl_xor(vd, m); }
            if (tx == 0 && row < M) {
                atomicAdd(&ssv[row], vs);
                atomicAdd(&sdv[row], vd);
            }
        }
    }
}

__global__ void bcomb_kernel(const float* __restrict__ b_in, const float* __restrict__ Wg1,
                             float* __restrict__ bcomb) {
    int n = threadIdx.x;  // 128
    float s = 0.f;
    for (int k = 0; k < 128; ++k) s += b_in[k] * Wg1[k * 128 + n];
    bcomb[n] = s;
}

// ---------------- cluster gather (coalesced) + split-K embedding GEMM ----------------
__global__ void gather_copy(const float* __restrict__ hA, const int* __restrict__ no,
                            float* __restrict__ flat) {
    int i = blockIdx.x * 256 + threadIdx.x;   // 0 .. 4194303
    int m = i >> 12, j = i & 4095;
    int node = no[(m << 5) + (j >> 7)];
    flat[i] = hA[(size_t)node * 128 + (j & 127)];
}

__global__ void emb_gemm(const float* __restrict__ flat, const float* __restrict__ W,
                         float* __restrict__ pbuf) {
    __shared__ float As[32][66];
    __shared__ float Bs[32][72];
    int t = threadIdx.x;
    int bx = blockIdx.x, by = blockIdx.y, sp = blockIdx.z;
    int tx = t & 15, ty = t >> 4;
    float acc[4][4] = {};
    int m0 = t >> 3;
    int kk4 = (t & 7) * 4;
    int kb0 = t >> 4;
    int n40 = (t & 15) * 4;
    int kbase = sp * 256;

    for (int k0 = 0; k0 < 256; k0 += 32) {
        __syncthreads();
        #pragma unroll
        for (int half = 0; half < 2; ++half) {
            int m = m0 + half * 32;
            int row = by * 64 + m;
            float4 v = *(const float4*)&flat[(size_t)row * 4096 + kbase + k0 + kk4];
            As[kk4 + 0][m] = v.x; As[kk4 + 1][m] = v.y;
            As[kk4 + 2][m] = v.z; As[kk4 + 3][m] = v.w;
        }
        #pragma unroll
        for (int half = 0; half < 2; ++half) {
            int kk = kb0 + half * 16;
            *(float4*)&Bs[kk][n40] = *(const float4*)&W[(size_t)(kbase + k0 + kk) * 128 + bx * 64 + n40];
        }
        __syncthreads();
        #pragma unroll
        for (int kk = 0; kk < 32; ++kk) {
            float a0 = As[kk][ty * 4 + 0];
            float a1 = As[kk][ty * 4 + 1];
            float a2 = As[kk][ty * 4 + 2];
            float a3 = As[kk][ty * 4 + 3];
            float4 b4 = *(float4*)&Bs[kk][tx * 4];
            acc[0][0] += a0 * b4.x; acc[0][1] += a0 * b4.y; acc[0][2] += a0 * b4.z; acc[0][3] += a0 * b4.w;
            acc[1][0] += a1 * b4.x; acc[1][1] += a1 * b4.y; acc[1][2] += a1 * b4.z; acc[1][3] += a1 * b4.w;
            acc[2][0] += a2 * b4.x; acc[2][1] += a2 * b4.y; acc[2][2] += a2 * b4.z; acc[2][3] += a2 * b4.w;
            acc[3][0] += a3 * b4.x; acc[3][1] += a3 * b4.y; acc[3][2] += a3 * b4.z; acc[3][3] += a3 * b4.w;
        }
    }
    float* C = pbuf + (size_t)sp * (1024 * 128);
    #pragma unroll
    for (int i = 0; i < 4; ++i) {
        int row = by * 64 + ty * 4 + i;
        #pragma unroll
        for (int j = 0; j < 4; ++j)
            C[(size_t)row * 128 + bx * 64 + tx * 4 + j] = acc[i][j];
    }
}

__global__ void emb_reduce(const float* __restrict__ pbuf, const float* __restrict__ b_emb,
                           float* __restrict__ out) {
    int i = blockIdx.x * 256 + threadIdx.x;   // 0..131071
    float s = b_emb[i & 127];
    #pragma unroll
    for (int sp = 0; sp < SPLIT; ++sp) s += pbuf[(size_t)sp * 131072 + i];
    out[i] = s;
}

// ---------------- GAT aggregation (fp32 gather, shfl-broadcast alphas) ----------------
// Wave = 1 node. Alphas precomputed lane-parallel; two half-waves each gather one
// 512B row (32 lanes x float4), 2 edges in flight per half-wave.
__global__ void gat_aggregate(const float* __restrict__ hW, const int* __restrict__ offs,
                              const int* __restrict__ csr, const float* __restrict__ ssrc,
                              const float* __restrict__ sdst, const float* __restrict__ bias,
                              float* __restrict__ out) {
    int lane = threadIdx.x & 63;
    int n = blockIdx.x * 4 + (threadIdx.x >> 6);
    int beg = offs[n], deg = offs[n + 1] - beg;   // deg >= 1 (self loop)
    float sd = sdst[n];
    // pass 1: segment max
    float mymax = -INFINITY;
    for (int c0 = 0; c0 < deg; c0 += 64) {
        if (c0 + lane < deg) {
            int s = csr[beg + c0 + lane];
            float e = ssrc[s] + sd;
            e = (e >= 0.f) ? e : 0.2f * e;
            mymax = fmaxf(mymax, e);
        }
    }
    #pragma unroll
    for (int m = 32; m >= 1; m >>= 1) mymax = fmaxf(mymax, __shfl_xor(mymax, m));
    // pass 2: denom
    float mysum = 0.f;
    for (int c0 = 0; c0 < deg; c0 += 64) {
        if (c0 + lane < deg) {
            int s = csr[beg + c0 + lane];
            float e = ssrc[s] + sd;
            e = (e >= 0.f) ? e : 0.2f * e;
            mysum += __expf(e - mymax);
        }
    }
    #pragma unroll
    for (int m = 32; m >= 1; m >>= 1) mysum += __shfl_xor(mysum, m);
    float inv = 1.f / mysum;
    // pass 3: weighted gather; half-wave h handles edges j ≡ h (mod 2)
    float ax = 0.f, ay = 0.f, az = 0.f, aw = 0.f;
    int half = lane >> 5, col = lane & 31;
    for (int c0 = 0; c0 < deg; c0 += 64) {
        int s = 0; float al = 0.f;
        if (c0 + lane < deg) {
            s = csr[beg + c0 + lane];
            float e = ssrc[s] + sd;
            e = (e >= 0.f) ? e : 0.2f * e;
            al = __expf(e - mymax) * inv;
        }
        int cend = min(64, deg - c0);
        int j = half;
        for (; j + 2 < cend; j += 4) {   // 2 edges per half-wave iteration
            int sj0 = __shfl(s, j);
            float aj0 = __shfl(al, j);
            int sj1 = __shfl(s, j + 2);
            float aj1 = __shfl(al, j + 2);
            float4 v0 = *(const float4*)&hW[(size_t)sj0 * 128 + col * 4];
            float4 v1 = *(const float4*)&hW[(size_t)sj1 * 128 + col * 4];
            ax += aj0 * v0.x; ay += aj0 * v0.y; az += aj0 * v0.z; aw += aj0 * v0.w;
            ax += aj1 * v1.x; ay += aj1 * v1.y; az += aj1 * v1.z; aw += aj1 * v1.w;
        }
        for (; j < cend; j += 2) {
            int sj = __shfl(s, j);
            float aj = __shfl(al, j);
            float4 v = *(const float4*)&hW[(size_t)sj * 128 + col * 4];
            ax += aj * v.x; ay += aj * v.y; az += aj * v.z; aw += aj * v.w;
        }
    }
    ax += __shfl_xor(ax, 32);
    ay += __shfl_xor(ay, 32);
    az += __shfl_xor(az, 32);
    aw += __shfl_xor(aw, 32);
    if (half == 0) {
        float4 ov;
        ov.x = ax + bias[col * 4 + 0];
        ov.y = ay + bias[col * 4 + 1];
        ov.z = az + bias[col * 4 + 2];
        ov.w = aw + bias[col * 4 + 3];
        *(float4*)&out[(size_t)n * 128 + col * 4] = ov;
    }
}

// ---------------- transformer kernels ----------------
// QKV col-slice: grid (257, 3). u = LN1(t) (recomputed per slice); qkv[:, s*128:+128] = u@Wq_s + bq_s
__global__ __launch_bounds__(256) void qkv_slice(
        const float* __restrict__ tb, const float* __restrict__ s1, const float* __restrict__ b1,
        const float* __restrict__ Wq, const float* __restrict__ bq, float* __restrict__ qkv) {
    __shared__ float u[4][128];
    __shared__ float red[4][2][128];
    __shared__ float ws[8192];   // 32 KB: 64 k-rows x 128 cols
    int t = threadIdx.x;
    int r0 = blockIdx.x * 4, sl = blockIdx.y;
    int col = t & 127, kh = t >> 7;
    {   // LN1: 64 lanes per row
        int rw = t >> 6, lane = t & 63;
        int row = r0 + rw;
        float a0 = 0.f, a1 = 0.f;
        if (row < SS) {
            a0 = tb[(size_t)row * 128 + lane];
            a1 = tb[(size_t)row * 128 + 64 + lane];
        }
        float sm = a0 + a1;
        #pragma unroll
        for (int m = 32; m >= 1; m >>= 1) sm += __shfl_xor(sm, m);
        float mean = sm * (1.f / 128.f);
        float d0 = a0 - mean, d1 = a1 - mean;
        float vv = d0 * d0 + d1 * d1;
        #pragma unroll
        for (int m = 32; m >= 1; m >>= 1) vv += __shfl_xor(vv, m);
        float rs = rsqrtf(vv * (1.f / 128.f) + 1e-5f);
        u[rw][lane] = d0 * rs * s1[lane] + b1[lane];
        u[rw][64 + lane] = d1 * rs * s1[64 + lane] + b1[64 + lane];
    }
    float acc[4] = {};
    for (int k0 = 0; k0 < 128; k0 += 64) {
        __syncthreads();
        const float* src = Wq + (size_t)k0 * 384 + sl * 128;
        #pragma unroll
        for (int i = 0; i < 8; ++i) {
            int idx = i * 256 + t;          // float4 index, 32 per k-row
            int kk = idx >> 5, c4 = (idx & 31) * 4;
            ((float4*)ws)[idx] = *(const float4*)&src[(size_t)kk * 384 + c4];
        }
        __syncthreads();
        int kb = kh * 32;
        #pragma unroll
        for (int kq = 0; kq < 32; kq += 4) {
            float a4[4][4];
            #pragma unroll
            for (int i = 0; i < 4; ++i)
                *(float4*)a4[i] = *(const float4*)&u[i][k0 + kb + kq];
            #pragma unroll
            for (int q = 0; q < 4; ++q) {
                float b = ws[(kb + kq + q) * 128 + col];
                #pragma unroll
                for (int i = 0; i < 4; ++i) acc[i] += a4[i][q] * b;
            }
        }
    }
    __syncthreads();
    #pragma unroll
    for (int i = 0; i < 4; ++i) red[i][kh][col] = acc[i];
    __syncthreads();
    if (t < 128) {
        float bqv = bq[sl * 128 + t];
        #pragma unroll
        for (int i = 0; i < 4; ++i) {
            int row = r0 + i;
            if (row < SS)
                qkv[(size_t)row * 384 + sl * 128 + t] = red[i][0][t] + red[i][1][t] + bqv;
        }
    }
}

// proj + residual + LN2: tn = o@Wo + bo + t; tb = tn + bf2 (FFN partials atomicAdd later); ub = LN2(tn)
__global__ __launch_bounds__(256) void proj_ln2(
        const float* __restrict__ ao, const float* __restrict__ Wo, const float* __restrict__ bo,
        const float* __restrict__ s2, const float* __restrict__ b2, const float* __restrict__ bf2,
        float* __restrict__ tb, float* __restrict__ ub) {
    __shared__ float bufA[4][128];
    __shared__ float tn[4][128];
    __shared__ float red[4][2][128];
    __shared__ float ws[8192];
    int t = threadIdx.x;
    int r0 = blockIdx.x * 4;
    int lane = t & 63;
    int col = t & 127, kh = t >> 7;
    {   // stage o rows
        int rw = t >> 6;
        int row = r0 + rw;
        float a0 = 0.f, a1 = 0.f;
        if (row < SS) {
            a0 = ao[(size_t)row * 128 + lane];
            a1 = ao[(size_t)row * 128 + 64 + lane];
        }
        bufA[rw][lane] = a0;
        bufA[rw][64 + lane] = a1;
    }
    float pp[4] = {};
    for (int k0 = 0; k0 < 128; k0 += 64) {
        __syncthreads();
        const float4* src = (const float4*)&Wo[(size_t)k0 * 128];
        #pragma unroll
        for (int i = 0; i < 8; ++i) ((float4*)ws)[i * 256 + t] = src[i * 256 + t];
        __syncthreads();
        int kb = kh * 32;
        #pragma unroll
        for (int kq = 0; kq < 32; kq += 4) {
            float a4[4][4];
            #pragma unroll
            for (int i = 0; i < 4; ++i)
                *(float4*)a4[i] = *(const float4*)&bufA[i][k0 + kb + kq];
            #pragma unroll
            for (int q = 0; q < 4; ++q) {
                float b = ws[(kb + kq + q) * 128 + col];
                #pragma unroll
                for (int i = 0; i < 4; ++i) pp[i] += a4[i][q] * b;
            }
        }
    }
    __syncthreads();
    #pragma unroll
    for (int i = 0; i < 4; ++i) red[i][kh][col] = pp[i];
    __syncthreads();
    if (t < 128) {
        #pragma unroll
        for (int i = 0; i < 4; ++i) {
            int row = r0 + i;
            float v = 0.f;
            if (row < SS) {
                v = red[i][0][t] + red[i][1][t] + bo[t] + tb[(size_t)row * 128 + t];
                tb[(size_t)row * 128 + t] = v + bf2[t];   // FFN partials accumulate on top
            }
            tn[i][t] = v;
        }
    }
    __syncthreads();
    {   // LN2(tn) -> ub
        int rw = t >> 6;
        int row = r0 + rw;
        float a0 = tn[rw][lane], a1 = tn[rw][64 + lane];
        float sm = a0 + a1;
        #pragma unroll
        for (int m = 32; m >= 1; m >>= 1) sm += __shfl_xor(sm, m);
        float mean = sm * (1.f / 128.f);
        float d0 = a0 - mean, d1 = a1 - mean;
        float vv = d0 * d0 + d1 * d1;
        #pragma unroll
        for (int m = 32; m >= 1; m >>= 1) vv += __shfl_xor(vv, m);
        float rs = rsqrtf(vv * (1.f / 128.f) + 1e-5f);
        if (row < SS) {
            ub[(size_t)row * 128 + lane] = d0 * rs * s2[lane] + b2[lane];
            ub[(size_t)row * 128 + 64 + lane] = d1 * rs * s2[64 + lane] + b2[64 + lane];
        }
    }
}

// FFN hidden-slice: grid (257, 4). g = gelu(u@Wf1[:,sl]+bf1[sl]); tb += g@Wf2[sl,:]
__global__ __launch_bounds__(256) void ffn_part(
        const float* __restrict__ ub, const float* __restrict__ Wf1, const float* __restrict__ bf1,
        const float* __restrict__ Wf2, float* __restrict__ tb) {
    __shared__ float u[4][128];
    __shared__ float g[4][128];
    __shared__ float red[4][2][128];
    __shared__ float ws[8192];
    int t = threadIdx.x;
    int r0 = blockIdx.x * 4, sl = blockIdx.y;
    int col = t & 127, kh = t >> 7;
    {   // load u rows
        int rw = t >> 6, lane = t & 63;
        int row = r0 + rw;
        float a0 = 0.f, a1 = 0.f;
        if (row < SS) {
            a0 = ub[(size_t)row * 128 + lane];
            a1 = ub[(size_t)row * 128 + 64 + lane];
        }
        u[rw][lane] = a0;
        u[rw][64 + lane] = a1;
    }
    // ffn1 slice
    float a1c[4] = {};
    for (int k0 = 0; k0 < 128; k0 += 64) {
        __syncthreads();
        const float* src = Wf1 + (size_t)k0 * 512 + sl * 128;
        #pragma unroll
        for (int i = 0; i < 8; ++i) {
            int idx = i * 256 + t;
            int kk = idx >> 5, c4 = (idx & 31) * 4;
            ((float4*)ws)[idx] = *(const float4*)&src[(size_t)kk * 512 + c4];
        }
        __syncthreads();
        int kb = kh * 32;
        #pragma unroll
        for (int kq = 0; kq < 32; kq += 4) {
            float a4[4][4];
            #pragma unroll
            for (int i = 0; i < 4; ++i)
                *(float4*)a4[i] = *(const float4*)&u[i][k0 + kb + kq];
            #pragma unroll
            for (int q = 0; q < 4; ++q) {
                float b = ws[(kb + kq + q) * 128 + col];
                #pragma unroll
                for (int i = 0; i < 4; ++i) a1c[i] += a4[i][q] * b;
            }
        }
    }
    __syncthreads();
    #pragma unroll
    for (int i = 0; i < 4; ++i) red[i][kh][col] = a1c[i];
    __syncthreads();
    if (t < 128) {
        float bv = bf1[sl * 128 + t];
        #pragma unroll
        for (int i = 0; i < 4; ++i)
            g[i][t] = gelu_f(red[i][0][t] + red[i][1][t] + bv);
    }
    // ffn2 slice: Wf2 rows [sl*128, sl*128+128) are contiguous
    float a2c[4] = {};
    for (int k0 = 0; k0 < 128; k0 += 64) {
        __syncthreads();
        const float4* src = (const float4*)&Wf2[(size_t)(sl * 128 + k0) * 128];
        #pragma unroll
        for (int i = 0; i < 8; ++i) ((float4*)ws)[i * 256 + t] = src[i * 256 + t];
        __syncthreads();
        int kb = kh * 32;
        #pragma unroll
        for (int kq = 0; kq < 32; kq += 4) {
            float a4[4][4];
            #pragma unroll
            for (int i = 0; i < 4; ++i)
                *(float4*)a4[i] = *(const float4*)&g[i][k0 + kb + kq];
            #pragma unroll
            for (int q = 0; q < 4; ++q) {
                float b = ws[(kb + kq + q) * 128 + col];
                #pragma unroll
                for (int i = 0; i < 4; ++i) a2c[i] += a4[i][q] * b;
            }
        }
    }
    __syncthreads();
    #pragma unroll
    for (int i = 0; i < 4; ++i) red[i][kh][col] = a2c[i];
    __syncthreads();
    if (t < 128) {
        #pragma unroll
        for (int i = 0; i < 4; ++i) {
            int row = r0 + i;
            if (row < SS)
                atomicAdd(&tb[(size_t)row * 128 + t], red[i][0][t] + red[i][1][t]);
        }
    }
}

// flash attention: dh=16, 16 lanes per query row, K/V tiles (64 keys) in LDS
__global__ void attn_kernel(const float* __restrict__ qkv, float* __restrict__ ao) {
    __shared__ float Kl[64][20];
    __shared__ float Vl[64][20];
    int h = blockIdx.y;
    int t = threadIdx.x;
    int sub = t & 15;
    int qr = blockIdx.x * 16 + (t >> 4);
    bool active = qr < SS;
    float q[16];
    if (active) {
        #pragma unroll
        for (int d = 0; d < 16; ++d) q[d] = qkv[(size_t)qr * 384 + h * 16 + d];
    }
    float m = -INFINITY, sum = 0.f;
    float acc[16] = {};
    for (int j0 = 0; j0 < SS; j0 += 64) {
        __syncthreads();
        int j = t >> 2, dg = (t & 3) * 4;
        if (j0 + j < SS) {
            const float* row = qkv + (size_t)(j0 + j) * 384 + h * 16 + dg;
            *(float4*)&Kl[j][dg] = *(const float4*)(row + 128);
            *(float4*)&Vl[j][dg] = *(const float4*)(row + 256);
        }
        __syncthreads();
        if (active) {
            int jmax = min(64, SS - j0);
            for (int jj = sub; jj < jmax; jj += 16) {
                float4 ka = *(const float4*)&Kl[jj][0];
                float4 kb = *(const float4*)&Kl[jj][4];
                float4 kc = *(const float4*)&Kl[jj][8];
                float4 kd = *(const float4*)&Kl[jj][12];
                float sc = q[0]*ka.x + q[1]*ka.y + q[2]*ka.z + q[3]*ka.w
                         + q[4]*kb.x + q[5]*kb.y + q[6]*kb.z + q[7]*kb.w
                         + q[8]*kc.x + q[9]*kc.y + q[10]*kc.z + q[11]*kc.w
                         + q[12]*kd.x + q[13]*kd.y + q[14]*kd.z + q[15]*kd.w;
                sc *= 0.25f;
                float4 va = *(const float4*)&Vl[jj][0];
                float4 vb = *(const float4*)&Vl[jj][4];
                float4 vc = *(const float4*)&Vl[jj][8];
                float4 vd = *(const float4*)&Vl[jj][12];
                float vv[16] = {va.x, va.y, va.z, va.w, vb.x, vb.y, vb.z, vb.w,
                                vc.x, vc.y, vc.z, vc.w, vd.x, vd.y, vd.z, vd.w};
                if (sc <= m) {
                    float p = __expf(sc - m);
                    sum += p;
                    #pragma unroll
                    for (int d = 0; d < 16; ++d) acc[d] += p * vv[d];
                } else {
                    float c = __expf(m - sc);
                    sum = sum * c + 1.f;
                    #pragma unroll
                    for (int d = 0; d < 16; ++d) acc[d] = acc[d] * c + vv[d];
                    m = sc;
                }
            }
        }
    }
    if (active) {
        #pragma unroll
        for (int msk = 1; msk < 16; msk <<= 1) {
            float mo = __shfl_xor(m, msk);
            float so = __shfl_xor(sum, msk);
            float vo[16];
            #pragma unroll
            for (int d = 0; d < 16; ++d) vo[d] = __shfl_xor(acc[d], msk);
            float mn = fmaxf(m, mo);
            float c1 = __expf(m - mn), c2 = __expf(mo - mn);
            sum = sum * c1 + so * c2;
            #pragma unroll
            for (int d = 0; d < 16; ++d) acc[d] = acc[d] * c1 + vo[d] * c2;
            m = mn;
        }
        if (sub == 0) {
            float inv = 1.f / sum;
            #pragma unroll
            for (int d = 0; d < 16; ++d) ao[(size_t)qr * 128 + h * 16 + d] = acc[d] * inv;
        }
    }
}

__global__ void cls_copy(const float* __restrict__ c, float* __restrict__ t) {
    t[threadIdx.x] = c[threadIdx.x];
}

__global__ void classifier_kernel(const float* __restrict__ t, const float* __restrict__ Wc,
                                  const float* __restrict__ bc, float* __restrict__ out) {
    int j = threadIdx.x;
    if (j < 10) {
        float a = bc[j];
        #pragma unroll
        for (int k = 0; k < 128; ++k) a += t[k] * Wc[k * 10 + j];
        out[j] = a;
    }
}

// ---------------- launch ----------------
extern "C" void kernel_launch(void* const* d_in, const int* in_sizes, int n_in,
                              void* d_out, int out_size, void* d_ws, size_t ws_size,
                              hipStream_t stream) {
    (void)in_sizes; (void)n_in; (void)out_size; (void)ws_size;
    const float* x     = (const float*)d_in[0];
    const int*   ei    = (const int*)d_in[1];
    const int*   nord  = (const int*)d_in[2];
    const float* W_in  = (const float*)d_in[3];
    const float* b_in  = (const float*)d_in[4];
    const float* Wg1   = (const float*)d_in[5];
    const float* as1   = (const float*)d_in[6];
    const float* ad1   = (const float*)d_in[7];
    const float* bg1   = (const float*)d_in[8];
    const float* Wg2   = (const float*)d_in[9];
    const float* as2   = (const float*)d_in[10];
    const float* ad2   = (const float*)d_in[11];
    const float* bg2   = (const float*)d_in[12];
    const float* W_emb = (const float*)d_in[13];
    const float* b_emb = (const float*)d_in[14];
    const float* clst  = (const float*)d_in[15];
    const float* ln1s  = (const float*)d_in[16];
    const float* ln1b  = (const float*)d_in[17];
    const float* Wqkv  = (const float*)d_in[18];
    const float* bqkv  = (const float*)d_in[19];
    const float* Wo    = (const float*)d_in[20];
    const float* bo    = (const float*)d_in[21];
    const float* ln2s  = (const float*)d_in[22];
    const float* ln2b  = (const float*)d_in[23];
    const float* Wf1   = (const float*)d_in[24];
    const float* bf1   = (const float*)d_in[25];
    const float* Wf2   = (const float*)d_in[26];
    const float* bf2   = (const float*)d_in[27];
    const float* Wc    = (const float*)d_in[28];
    const float* bc    = (const float*)d_in[29];

    char* w = (char*)d_ws;
    size_t o = 0;
    auto ALLOC = [&](size_t nbytes) -> char* {
        char* p = w + o;
        o += (nbytes + 255) & ~(size_t)255;
        return p;
    };
    int*   cnt   = (int*)ALLOC((size_t)NN * 4);
    int*   fill  = (int*)ALLOC((size_t)NN * 4);            // contiguous with cnt
    int*   offs  = (int*)ALLOC((size_t)(NN + 1) * 4);
    int*   csr   = (int*)ALLOC((size_t)EN_TOT * 4);
    float* hA    = (float*)ALLOC((size_t)NN * 128 * 4);    // GAT2 output
    float* hW    = (float*)ALLOC((size_t)NN * 128 * 4);    // also pbuf
    float* h1    = (float*)ALLOC((size_t)NN * 128 * 4);    // also flat (16MB)
    float* ssrc  = (float*)ALLOC((size_t)NN * 4);
    float* sdst  = (float*)ALLOC((size_t)NN * 4);          // contiguous with ssrc
    float* tbuf  = (float*)ALLOC((size_t)SS * 128 * 4);
    float* ubuf  = (float*)ALLOC((size_t)SS * 128 * 4);
    float* qkvb  = (float*)ALLOC((size_t)SS * 384 * 4);
    float* aob   = (float*)ALLOC((size_t)SS * 128 * 4);
    float* Wcomb = (float*)ALLOC((size_t)128 * 128 * 4);
    float* bcomb = (float*)ALLOC((size_t)128 * 4);
    float* pbuf  = hW;
    float* flat  = h1;

    dim3 blk(256);
    int egrid = (EN_TOT + 255) / 256;

    // CSR by dst
    hipMemsetAsync(cnt, 0, (size_t)NN * 8, stream);
    hist_kernel<<<egrid, blk, 0, stream>>>(ei, cnt);
    scan_kernel<<<1, 1024, 0, stream>>>(cnt, offs);
    scatter_kernel<<<egrid, blk, 0, stream>>>(ei, offs, fill, csr);

    // Wcomb = W_in@Wg1 ; bcomb = b_in@Wg1
    gemm_f32<<<dim3(2, 2), blk, 0, stream>>>(W_in, Wg1, nullptr, nullptr, Wcomb,
                                             nullptr, nullptr, nullptr, nullptr,
                                             128, 128, 128);
    bcomb_kernel<<<1, 128, 0, stream>>>(b_in, Wg1, bcomb);

    // GAT 1: hW = x@Wcomb + bcomb (+ fused dots)
    hipMemsetAsync(ssrc, 0, (size_t)NN * 8, stream);
    gemm_f32<<<dim3(2, 512), blk, 0, stream>>>(x, Wcomb, bcomb, nullptr, hW,
                                               as1, ad1, ssrc, sdst,
                                               NN, 128, 128);
    gat_aggregate<<<8192, blk, 0, stream>>>(hW, offs, csr, ssrc, sdst, bg1, h1);
    // GAT 2
    hipMemsetAsync(ssrc, 0, (size_t)NN * 8, stream);
    gemm_f32<<<dim3(2, 512), blk, 0, stream>>>(h1, Wg2, nullptr, nullptr, hW,
                                               as2, ad2, ssrc, sdst,
                                               NN, 128, 128);
    gat_aggregate<<<8192, blk, 0, stream>>>(hW, offs, csr, ssrc, sdst, bg2, hA);

    // tokens: coalesced gather then split-K GEMM
    cls_copy<<<1, 128, 0, stream>>>(clst, tbuf);
    gather_copy<<<16384, blk, 0, stream>>>(hA, nord, flat);
    emb_gemm<<<dim3(2, 16, SPLIT), blk, 0, stream>>>(flat, W_emb, pbuf);
    emb_reduce<<<512, blk, 0, stream>>>(pbuf, b_emb, tbuf + 128);

    for (int l = 0; l < LL; ++l) {
        qkv_slice<<<dim3(257, 3), blk, 0, stream>>>(tbuf, ln1s + l * 128, ln1b + l * 128,
                                                    Wqkv + (size_t)l * 128 * 384, bqkv + l * 384, qkvb);
        attn_kernel<<<dim3(65, 8), blk, 0, stream>>>(qkvb, aob);
        proj_ln2<<<257, blk, 0, stream>>>(aob, Wo + (size_t)l * 128 * 128, bo + l * 128,
                                          ln2s + l * 128, ln2b + l * 128, bf2 + l * 128,
                                          tbuf, ubuf);
        ffn_part<<<dim3(257, 4), blk, 0, stream>>>(ubuf, Wf1 + (size_t)l * 128 * 512, bf1 + l * 512,
                                                   Wf2 + (size_t)l * 512 * 128, tbuf);
    }
    classifier_kernel<<<1, 64, 0, stream>>>(tbuf, Wc, bc, (float*)d_out);
}